// Round 2
// baseline (3754.546 us; speedup 1.0000x reference)
//
#include <hip/hip_runtime.h>
#include <stdint.h>

// ResRnn: T=128 sequential steps of  h=|s@W1^T+b1|; s'=0.9*shift(s)+0.1*(h@W2^T+b2)
// Persistent kernel: 256 WGs (1/CU), 4 independent batch-groups of 64 WGs,
// bf16 weights resident in VGPRs as MFMA B-frags.
// R6 (restored): NO group barrier. Pure dataflow: per-chunk monotone generation
//     flags at 64B stride, tid0 store AFTER __syncthreads (which drains all 4
//     waves' sc1 stores via vmcnt(0)-before-s_barrier). R7's packed flags +
//     per-wave atomic counters REVERTED: atomics RMW-contended on hot lines
//     (2425 -> 3180 us regression).
// R8 (this round): operand reads go through L2 again.
//     Producers still write h/Sb/Sf via agent-scope sc1 stores (write-through
//     to MALL, ordered before the flag by the pre-barrier vmcnt(0) drain).
//     Consumers: after the flag wait succeeds, ONE acquire fence at agent
//     scope (__builtin_amdgcn_fence -> L0+L2 invalidate), then PLAIN CACHED
//     loads for h/Sb/Sf. Every post-invalidate L2 fill comes from the MALL
//     (fresh); 32 WGs/XCD share one L2 copy instead of 32 MALL round trips.
//     Kept from R7: epilogue fp32 prev (SfOld[chunk-2]) hoisted to right
//     after the phase-1 wait (lane-16 chunk-2 check covers it) -> its load
//     latency hides under phase-1 MFMA + h-exchange + phase-2.
// Buffer safety unchanged from R6: S ping-pong + single h buffer.

#define NSTEPS 128
#define NB 128
#define WID 2048
#define SS 1984   // recurrent state width (WIDTH - INPUT_SIZE)

typedef __attribute__((ext_vector_type(8))) short short8;
typedef __attribute__((ext_vector_type(4))) short short4v;
typedef __attribute__((ext_vector_type(4))) float f32x4;
typedef unsigned long long u64;

static __device__ __forceinline__ short f2bf(float f) {
  union { float f; unsigned u; } v; v.f = f;
  unsigned r = (v.u + 0x7fffu + ((v.u >> 16) & 1u)) >> 16;  // RNE
  return (short)r;
}

static __device__ __forceinline__ short8 pack8(f32x4 lo, f32x4 hi) {
  short8 r;
  r[0] = f2bf(lo[0]); r[1] = f2bf(lo[1]); r[2] = f2bf(lo[2]); r[3] = f2bf(lo[3]);
  r[4] = f2bf(hi[0]); r[5] = f2bf(hi[1]); r[6] = f2bf(hi[2]); r[7] = f2bf(hi[3]);
  return r;
}

// write-through store to the agent coherence point (LLC); does not dirty L2
static __device__ __forceinline__ void ast64(void* p, u64 v) {
  __hip_atomic_store((u64*)p, v, __ATOMIC_RELAXED, __HIP_MEMORY_SCOPE_AGENT);
}
// LLC-direct coherent load (flags only — must never be served stale from L2)
static __device__ __forceinline__ unsigned ald32(const unsigned* p) {
  return __hip_atomic_load(p, __ATOMIC_RELAXED, __HIP_MEMORY_SCOPE_AGENT);
}
// acquire fence: waits outstanding loads, invalidates L0+L2 so subsequent
// PLAIN loads refill from the MALL (which producers wrote through to)
static __device__ __forceinline__ void acq_fence() {
  __builtin_amdgcn_fence(__ATOMIC_ACQUIRE, "agent");
}

__global__ __launch_bounds__(256, 1)
void resrnn_kernel(const float* __restrict__ inp, const float* __restrict__ W1,
                   const float* __restrict__ b1f, const float* __restrict__ W2,
                   const float* __restrict__ b2f, float* __restrict__ out,
                   unsigned char* __restrict__ ws)
{
  const int tid   = threadIdx.x;
  const int bid   = blockIdx.x;
  const int group = bid & 3;        // 4 independent batch groups (32 rows each)
  const int chunk = bid >> 2;       // 64 N-chunks of 32 cols
  const int mbase = group * 32;
  const int n0    = chunk * 32;
  const int wave  = tid >> 6;
  const int lane  = tid & 63;
  const int l15   = lane & 15;
  const int q8    = (lane >> 4) * 8;
  const int kb    = wave * 512;     // K split 4 ways across waves

  // per-group flag arrays: 64 chunks x 64B slots (16 u32 stride), monotone gens
  unsigned* sgen = (unsigned*)(ws + group * 8192);          // S-chunk ready: value t+1
  unsigned* hgen = (unsigned*)(ws + group * 8192 + 4096);   // h-chunk ready: value t+1
  float* Sf0 = (float*)(ws + 32768);                 // fp32 state master, ping
  float* Sf1 = (float*)(ws + 32768 + 1015808);       // pong
  short* Sb0 = (short*)(ws + 32768 + 2031616);       // bf16 state, ping
  short* Sb1 = (short*)(ws + 32768 + 2539520);       // pong
  short* hb  = (short*)(ws + 32768 + 3047424);       // bf16 h buffer [128][2048]

  __shared__ float red[4][16][65];  // +1 pad: conflict-free cross-wave reduce

  // ---- one-time: load & convert weight B-fragments into registers ----
  // B-frag layout (verified m89): n = lane&15 (row of W), k = (lane>>4)*8+j contiguous
  short8 B1[16][2], B2[16][2];
#pragma unroll
  for (int ks = 0; ks < 16; ++ks) {
#pragma unroll
    for (int nt = 0; nt < 2; ++nt) {
      const float* p1 = W1 + (size_t)(n0 + nt * 16 + l15) * WID + (kb + ks * 32 + q8);
      B1[ks][nt] = pack8(*(const f32x4*)p1, *(const f32x4*)(p1 + 4));
      const float* p2 = W2 + (size_t)(n0 + nt * 16 + l15) * WID + (kb + ks * 32 + q8);
      B2[ks][nt] = pack8(*(const f32x4*)p2, *(const f32x4*)(p2 + 4));
    }
  }

  const int m0 = mbase + l15;        // A-frag rows (m-tile 0)
  const int m1 = mbase + 16 + l15;   // m-tile 1

  const int o    = tid * 4;          // epilogue: 4 outputs per thread of 32x32 tile
  const int ml   = o >> 5;
  const int nl   = o & 31;
  const int mrow = mbase + ml;
  const int c0   = n0 + nl;          // this thread's absolute output column

  // biases for this thread's 4 output columns, loaded once (constant over t)
  const f32x4 b1r = *(const f32x4*)(b1f + n0 + nl);
  const f32x4 b2r = *(const f32x4*)(b2f + n0 + nl);

  // phase-1 wait setup: wave w, iter ks reads S-chunk 16w+ks-2 (ks<2,w==0 -> inp).
  // Lanes 0..15 poll the 16 A-operand producers; lane 16 polls chunk-2
  // (covers the hoisted fp32 prev read).
  const int p1pc = 16 * wave + l15 - 2;
  const bool p1needA = (lane < 16) && (p1pc >= 0);
  const unsigned* p1fpA = sgen + (p1pc < 0 ? 0 : p1pc) * 16;
  const bool p1needB = (lane == 16) && (chunk >= 2);
  const unsigned* p1fpB = sgen + (chunk >= 2 ? chunk - 2 : 0) * 16;
  // phase-2 wait setup: lanes 0..15 poll h-chunks 16w+l15
  const unsigned* p2fp = hgen + (16 * wave + l15) * 16;

#pragma unroll 1
  for (int t = 0; t < NSTEPS; ++t) {
    const float* SfOld = (t & 1) ? Sf1 : Sf0;
    float*       SfNew = (t & 1) ? Sf0 : Sf1;
    const short* SbOld = (t & 1) ? Sb1 : Sb0;
    short*       SbNew = (t & 1) ? Sb0 : Sb1;

    // ================= phase 1: u = s_in @ W1^T ; h = |u + b1| =================
    if (t > 0) {  // wait for producers (value >= t), then invalidate L0/L2 once
      const unsigned tgt = (unsigned)t;
      for (;;) {
        unsigned v = tgt;
        if (p1needA)      v = ald32(p1fpA);
        else if (p1needB) v = ald32(p1fpB);
        if (__ballot(v >= tgt) == ~0ull) break;
        __builtin_amdgcn_s_sleep(1);
      }
      acq_fence();   // L2 refills after this point come from the MALL (fresh)
    }

    // hoisted epilogue prev: producer (chunk-2, gen t) guaranteed by the
    // phase-1 wait (lane-16 check); PLAIN cached load after the fence.
    f32x4 prevv;
    if (c0 < 64) {            // shifted-in x_t (exact fp32, read-only input)
      prevv = *(const f32x4*)(inp + ((size_t)t * NB + mrow) * 64 + c0);
    } else if (t > 0) {       // fp32 master state, L2-cached post-invalidate
      prevv = *(const f32x4*)(SfOld + (size_t)mrow * SS + (c0 - 64));
    } else {
      prevv = f32x4{0.f, 0.f, 0.f, 0.f};
    }

    f32x4 a00{}, a01{}, a10{}, a11{};
#pragma unroll
    for (int ks = 0; ks < 16; ++ks) {
      short8 x0, x1;
      bool act = true;
      if (kb == 0 && ks < 2) {               // k in [0,64): x_t columns (read-only input)
        const float* p0 = inp + ((size_t)t * NB + m0) * 64 + (ks * 32 + q8);
        const float* p1 = inp + ((size_t)t * NB + m1) * 64 + (ks * 32 + q8);
        x0 = pack8(*(const f32x4*)p0, *(const f32x4*)(p0 + 4));
        x1 = pack8(*(const f32x4*)p1, *(const f32x4*)(p1 + 4));
      } else if (t > 0) {                    // k in [64,2048): recurrent bf16 state,
        x0 = *(const short8*)(SbOld + (size_t)m0 * SS + (kb + ks * 32 - 64 + q8));  // L2-cached
        x1 = *(const short8*)(SbOld + (size_t)m1 * SS + (kb + ks * 32 - 64 + q8));
      } else act = false;                    // t==0: state is zero
      if (act) {
        a00 = __builtin_amdgcn_mfma_f32_16x16x32_bf16(x0, B1[ks][0], a00, 0, 0, 0);
        a01 = __builtin_amdgcn_mfma_f32_16x16x32_bf16(x0, B1[ks][1], a01, 0, 0, 0);
        a10 = __builtin_amdgcn_mfma_f32_16x16x32_bf16(x1, B1[ks][0], a10, 0, 0, 0);
        a11 = __builtin_amdgcn_mfma_f32_16x16x32_bf16(x1, B1[ks][1], a11, 0, 0, 0);
      }
    }
#pragma unroll
    for (int r = 0; r < 4; ++r) {            // ridx = mt*8 + nt*4 + r
      red[wave][r][lane]      = a00[r];
      red[wave][4 + r][lane]  = a01[r];
      red[wave][8 + r][lane]  = a10[r];
      red[wave][12 + r][lane] = a11[r];
    }
    __syncthreads();
    {
      short4v hv;
#pragma unroll
      for (int j = 0; j < 4; ++j) {
        const int nn   = nl + j;
        const int lidx = ((ml >> 2) & 3) * 16 + (nn & 15);   // C layout: lane=(row>>2)*16+col
        const int ridx = (ml >> 4) * 8 + (nn >> 4) * 4 + (ml & 3);
        float s = red[0][ridx][lidx] + red[1][ridx][lidx]
                + red[2][ridx][lidx] + red[3][ridx][lidx];
        s += b1r[j];
        hv[j] = f2bf(fabsf(s));
      }
      union { short4v s; u64 u; } hu; hu.s = hv;
      ast64(hb + (size_t)mrow * WID + (n0 + nl), hu.u);
    }
    __syncthreads();   // all 4 waves' h stores drained (vmcnt0) before signal
    if (tid == 0)
      __hip_atomic_store(hgen + chunk * 16, (unsigned)t + 1,
                         __ATOMIC_RELAXED, __HIP_MEMORY_SCOPE_AGENT);

    // ================= phase 2: g = h @ W2^T ; state update =================
    {  // wait: this wave's 16 h-producers (>= t+1), then invalidate L0/L2
      const unsigned tgt = (unsigned)t + 1;
      for (;;) {
        unsigned v = tgt;
        if (lane < 16) v = ald32(p2fp);
        if (__ballot(v >= tgt) == ~0ull) break;
        __builtin_amdgcn_s_sleep(1);
      }
      acq_fence();
    }
    f32x4 c00{}, c01{}, c10{}, c11{};
    {
      const short* h0 = hb + (size_t)m0 * WID + (kb + q8);
      const short* h1 = hb + (size_t)m1 * WID + (kb + q8);
#pragma unroll
      for (int ks = 0; ks < 16; ++ks) {
        short8 x0 = *(const short8*)(h0 + ks * 32);    // L2-cached post-invalidate
        short8 x1 = *(const short8*)(h1 + ks * 32);
        c00 = __builtin_amdgcn_mfma_f32_16x16x32_bf16(x0, B2[ks][0], c00, 0, 0, 0);
        c01 = __builtin_amdgcn_mfma_f32_16x16x32_bf16(x0, B2[ks][1], c01, 0, 0, 0);
        c10 = __builtin_amdgcn_mfma_f32_16x16x32_bf16(x1, B2[ks][0], c10, 0, 0, 0);
        c11 = __builtin_amdgcn_mfma_f32_16x16x32_bf16(x1, B2[ks][1], c11, 0, 0, 0);
      }
    }
#pragma unroll
    for (int r = 0; r < 4; ++r) {
      red[wave][r][lane]      = c00[r];
      red[wave][4 + r][lane]  = c01[r];
      red[wave][8 + r][lane]  = c10[r];
      red[wave][12 + r][lane] = c11[r];
    }
    __syncthreads();
    if (t < NSTEPS - 1) {
      if (n0 < SS) {   // cols >= SS are dropped by the shift (except final step)
        f32x4 gv;
#pragma unroll
        for (int j = 0; j < 4; ++j) {
          const int nn   = nl + j;
          const int lidx = ((ml >> 2) & 3) * 16 + (nn & 15);
          const int ridx = (ml >> 4) * 8 + (nn >> 4) * 4 + (ml & 3);
          gv[j] = red[0][ridx][lidx] + red[1][ridx][lidx]
                + red[2][ridx][lidx] + red[3][ridx][lidx] + b2r[j];
        }
        f32x4 sv; short4v sb;
#pragma unroll
        for (int j = 0; j < 4; ++j) {
          float vv = 0.9f * prevv[j] + 0.1f * gv[j];
          sv[j] = vv; sb[j] = f2bf(vv);
        }
        union { f32x4 f; u64 u[2]; } sfu; sfu.f = sv;
        float* pf = SfNew + (size_t)mrow * SS + c0;
        ast64(pf, sfu.u[0]);
        ast64(pf + 2, sfu.u[1]);
        union { short4v s; u64 u; } sbu; sbu.s = sb;
        ast64(SbNew + (size_t)mrow * SS + c0, sbu.u);
      }
      __syncthreads();   // all 4 waves' S stores drained before signal
      if (tid == 0 && chunk < 62)
        __hip_atomic_store(sgen + chunk * 16, (unsigned)t + 1,
                           __ATOMIC_RELAXED, __HIP_MEMORY_SCOPE_AGENT);
    } else {
      // final step: out[m, :] = 0.9*s_in[m, 1984+o] + 0.1*(g+b2)[m, 1984+o]
      if (n0 >= SS) {
        f32x4 gv;
#pragma unroll
        for (int j = 0; j < 4; ++j) {
          const int nn   = nl + j;
          const int lidx = ((ml >> 2) & 3) * 16 + (nn & 15);
          const int ridx = (ml >> 4) * 8 + (nn >> 4) * 4 + (ml & 3);
          gv[j] = red[0][ridx][lidx] + red[1][ridx][lidx]
                + red[2][ridx][lidx] + red[3][ridx][lidx] + b2r[j];
        }
        f32x4 ov;
#pragma unroll
        for (int j = 0; j < 4; ++j) ov[j] = 0.9f * prevv[j] + 0.1f * gv[j];
        *(f32x4*)(out + (size_t)mrow * 64 + (c0 - SS)) = ov;
      }
    }
  }
}

extern "C" void kernel_launch(void* const* d_in, const int* in_sizes, int n_in,
                              void* d_out, int out_size, void* d_ws, size_t ws_size,
                              hipStream_t stream)
{
  (void)in_sizes; (void)n_in; (void)out_size; (void)ws_size;
  const float* inp = (const float*)d_in[0];
  const float* W1  = (const float*)d_in[1];
  const float* b1  = (const float*)d_in[2];
  const float* W2  = (const float*)d_in[3];
  const float* b2  = (const float*)d_in[4];
  float* out = (float*)d_out;

  // zero the flag area (ws is re-poisoned to 0xAA before every timed launch)
  hipMemsetAsync(d_ws, 0, 32768, stream);
  resrnn_kernel<<<dim3(256), dim3(256), 0, stream>>>(
      inp, W1, b1, W2, b2, out, (unsigned char*)d_ws);
}

// Round 4
// 2470.518 us; speedup vs baseline: 1.5197x; 1.5197x over previous
//
#include <hip/hip_runtime.h>
#include <stdint.h>

// ResRnn: T=128 sequential steps of  h=|s@W1^T+b1|; s'=0.9*shift(s)+0.1*(h@W2^T+b2)
// Persistent kernel: 256 WGs (1/CU), 4 independent batch-groups of 64 WGs,
// bf16 weights resident in VGPRs as MFMA B-frags.
// R2/R4: cross-WG data moved via RELAXED agent-scope atomics (sc1, write-through
//     to LLC; LLC-direct loads) -> no release/acquire cache ops anywhere.
// R6 (= 2425us baseline, fully restored here): NO group barrier. Pure dataflow:
//     per-chunk monotone generation flags, 64B-strided slots, tid0 store AFTER
//     __syncthreads (drains all 4 waves' sc1 stores via vmcnt(0)-before-barrier).
// R7 REVERTED (packed flags + per-wave atomic counters: 3180us — RMW contention
//     on shared hot lines). R8 REVERTED (acquire-fence + cached operand loads:
//     3754us — 32 WGs/XCD wipe the L2 every ~300ns, zero sharing materialized,
//     paid 65k fence drains; FETCH_SIZE stayed flat = no L2-fill surge).
// R9/R10 (R3 was an infra failure — byte-identical resubmit; strict isolation
//     on the R6 base):
//   (1) prevv HOIST: the epilogue fp32 SfOld read moves from inside the
//       phase-2 epilogue (where its MALL RT was fully exposed between the
//       reduce barrier and the S stores) to right after the phase-1 wait.
//       Coverage: lane-16 chunk-2 check moves from phase-2's wait (R6's
//       p2needs) into phase-1's wait. Same condition, strictly earlier,
//       latency hidden under phase-1 MFMA + h exchange + phase-2.
//   (2) STICKY POLL: a lane stops re-loading its flag once it has seen
//       ready (exit condition identical: all lanes satisfied). Strictly
//       fewer poll loads; zero protocol change.
// Buffer safety unchanged: S ping-pong + single h buffer.

#define NSTEPS 128
#define NB 128
#define WID 2048
#define SS 1984   // recurrent state width (WIDTH - INPUT_SIZE)

typedef __attribute__((ext_vector_type(8))) short short8;
typedef __attribute__((ext_vector_type(4))) short short4v;
typedef __attribute__((ext_vector_type(4))) float f32x4;
typedef unsigned long long u64;

static __device__ __forceinline__ short f2bf(float f) {
  union { float f; unsigned u; } v; v.f = f;
  unsigned r = (v.u + 0x7fffu + ((v.u >> 16) & 1u)) >> 16;  // RNE
  return (short)r;
}

static __device__ __forceinline__ short8 pack8(f32x4 lo, f32x4 hi) {
  short8 r;
  r[0] = f2bf(lo[0]); r[1] = f2bf(lo[1]); r[2] = f2bf(lo[2]); r[3] = f2bf(lo[3]);
  r[4] = f2bf(hi[0]); r[5] = f2bf(hi[1]); r[6] = f2bf(hi[2]); r[7] = f2bf(hi[3]);
  return r;
}

// write-through store to the agent coherence point (LLC); does not dirty L2
static __device__ __forceinline__ void ast64(void* p, u64 v) {
  __hip_atomic_store((u64*)p, v, __ATOMIC_RELAXED, __HIP_MEMORY_SCOPE_AGENT);
}
// LLC-direct coherent loads (bypass possibly-stale L1/L2)
static __device__ __forceinline__ u64 ald64(const void* p) {
  return __hip_atomic_load((const u64*)p, __ATOMIC_RELAXED, __HIP_MEMORY_SCOPE_AGENT);
}
static __device__ __forceinline__ unsigned ald32(const unsigned* p) {
  return __hip_atomic_load(p, __ATOMIC_RELAXED, __HIP_MEMORY_SCOPE_AGENT);
}
static __device__ __forceinline__ short8 ald_s8(const void* p) {
  union { u64 u[2]; short8 s; } r;
  r.u[0] = ald64((const char*)p);
  r.u[1] = ald64((const char*)p + 8);
  return r.s;
}
static __device__ __forceinline__ f32x4 ald_f4(const void* p) {
  union { u64 u[2]; f32x4 f; } r;
  r.u[0] = ald64((const char*)p);
  r.u[1] = ald64((const char*)p + 8);
  return r.f;
}

__global__ __launch_bounds__(256, 1)
void resrnn_kernel(const float* __restrict__ inp, const float* __restrict__ W1,
                   const float* __restrict__ b1f, const float* __restrict__ W2,
                   const float* __restrict__ b2f, float* __restrict__ out,
                   unsigned char* __restrict__ ws)
{
  const int tid   = threadIdx.x;
  const int bid   = blockIdx.x;
  const int group = bid & 3;        // 4 independent batch groups (32 rows each)
  const int chunk = bid >> 2;       // 64 N-chunks of 32 cols
  const int mbase = group * 32;
  const int n0    = chunk * 32;
  const int wave  = tid >> 6;
  const int lane  = tid & 63;
  const int l15   = lane & 15;
  const int q8    = (lane >> 4) * 8;
  const int kb    = wave * 512;     // K split 4 ways across waves

  // per-group flag arrays: 64 chunks x 64B slots (16 u32 stride), monotone gens
  unsigned* sgen = (unsigned*)(ws + group * 8192);          // S-chunk ready: value t+1
  unsigned* hgen = (unsigned*)(ws + group * 8192 + 4096);   // h-chunk ready: value t+1
  float* Sf0 = (float*)(ws + 32768);                 // fp32 state master, ping
  float* Sf1 = (float*)(ws + 32768 + 1015808);       // pong
  short* Sb0 = (short*)(ws + 32768 + 2031616);       // bf16 state, ping
  short* Sb1 = (short*)(ws + 32768 + 2539520);       // pong
  short* hb  = (short*)(ws + 32768 + 3047424);       // bf16 h buffer [128][2048]

  __shared__ float red[4][16][65];  // +1 pad: conflict-free cross-wave reduce

  // ---- one-time: load & convert weight B-fragments into registers ----
  // B-frag layout (verified m89): n = lane&15 (row of W), k = (lane>>4)*8+j contiguous
  short8 B1[16][2], B2[16][2];
#pragma unroll
  for (int ks = 0; ks < 16; ++ks) {
#pragma unroll
    for (int nt = 0; nt < 2; ++nt) {
      const float* p1 = W1 + (size_t)(n0 + nt * 16 + l15) * WID + (kb + ks * 32 + q8);
      B1[ks][nt] = pack8(*(const f32x4*)p1, *(const f32x4*)(p1 + 4));
      const float* p2 = W2 + (size_t)(n0 + nt * 16 + l15) * WID + (kb + ks * 32 + q8);
      B2[ks][nt] = pack8(*(const f32x4*)p2, *(const f32x4*)(p2 + 4));
    }
  }

  const int m0 = mbase + l15;        // A-frag rows (m-tile 0)
  const int m1 = mbase + 16 + l15;   // m-tile 1

  const int o    = tid * 4;          // epilogue: 4 outputs per thread of 32x32 tile
  const int ml   = o >> 5;
  const int nl   = o & 31;
  const int mrow = mbase + ml;
  const int c0   = n0 + nl;          // this thread's absolute output column

  // biases for this thread's 4 output columns, loaded once (constant over t)
  const f32x4 b1r = *(const f32x4*)(b1f + n0 + nl);
  const f32x4 b2r = *(const f32x4*)(b2f + n0 + nl);

  // phase-1 wait setup: wave w, iter ks reads S-chunk 16w+ks-2 (ks<2,w==0 -> inp).
  // Lanes 0..15 poll the 16 A-operand producers; lane 16 polls chunk-2
  // (covers the hoisted fp32 prev read — was R6's phase-2 p2needs).
  const int p1pc = 16 * wave + l15 - 2;
  const bool p1needA = (lane < 16) && (p1pc >= 0);
  const bool p1needB = (lane == 16) && (chunk >= 2);
  const unsigned* p1fp =
      p1needA ? (sgen + p1pc * 16)
              : (sgen + (chunk >= 2 ? chunk - 2 : 0) * 16);  // lane16 slot (or dummy)
  // phase-2 wait setup: lanes 0..15 poll h-chunks 16w+l15
  const unsigned* p2fp = hgen + (16 * wave + l15) * 16;

#pragma unroll 1
  for (int t = 0; t < NSTEPS; ++t) {
    const float* SfOld = (t & 1) ? Sf1 : Sf0;
    float*       SfNew = (t & 1) ? Sf0 : Sf1;
    const short* SbOld = (t & 1) ? Sb1 : Sb0;
    short*       SbNew = (t & 1) ? Sb0 : Sb1;

    // ================= phase 1: u = s_in @ W1^T ; h = |u + b1| =================
    if (t > 0) {  // wait for producers (value >= t); sticky per-lane poll
      const unsigned tgt = (unsigned)t;
      bool pend = p1needA || p1needB;
      for (;;) {
        if (pend && ald32(p1fp) >= tgt) pend = false;
        if (__ballot(pend) == 0ull) break;
        __builtin_amdgcn_s_sleep(1);
      }
    }

    // hoisted epilogue prev: producer (chunk-2, gen t) guaranteed by the
    // phase-1 wait (lane-16 check); LLC-direct load, latency hidden under
    // phase-1 MFMA + h exchange + phase-2.
    f32x4 prevv;
    if (c0 < 64) {            // shifted-in x_t (exact fp32, read-only input)
      prevv = *(const f32x4*)(inp + ((size_t)t * NB + mrow) * 64 + c0);
    } else if (t > 0) {       // fp32 master state, LLC-direct (written via sc1)
      prevv = ald_f4(SfOld + (size_t)mrow * SS + (c0 - 64));
    } else {
      prevv = f32x4{0.f, 0.f, 0.f, 0.f};
    }

    f32x4 a00{}, a01{}, a10{}, a11{};
#pragma unroll
    for (int ks = 0; ks < 16; ++ks) {
      short8 x0, x1;
      bool act = true;
      if (kb == 0 && ks < 2) {               // k in [0,64): x_t columns (read-only input,
        const float* p0 = inp + ((size_t)t * NB + m0) * 64 + (ks * 32 + q8);   // normal cached)
        const float* p1 = inp + ((size_t)t * NB + m1) * 64 + (ks * 32 + q8);
        x0 = pack8(*(const f32x4*)p0, *(const f32x4*)(p0 + 4));
        x1 = pack8(*(const f32x4*)p1, *(const f32x4*)(p1 + 4));
      } else if (t > 0) {                    // k in [64,2048): recurrent bf16 state, LLC-direct
        x0 = ald_s8(SbOld + (size_t)m0 * SS + (kb + ks * 32 - 64 + q8));
        x1 = ald_s8(SbOld + (size_t)m1 * SS + (kb + ks * 32 - 64 + q8));
      } else act = false;                    // t==0: state is zero
      if (act) {
        a00 = __builtin_amdgcn_mfma_f32_16x16x32_bf16(x0, B1[ks][0], a00, 0, 0, 0);
        a01 = __builtin_amdgcn_mfma_f32_16x16x32_bf16(x0, B1[ks][1], a01, 0, 0, 0);
        a10 = __builtin_amdgcn_mfma_f32_16x16x32_bf16(x1, B1[ks][0], a10, 0, 0, 0);
        a11 = __builtin_amdgcn_mfma_f32_16x16x32_bf16(x1, B1[ks][1], a11, 0, 0, 0);
      }
    }
#pragma unroll
    for (int r = 0; r < 4; ++r) {            // ridx = mt*8 + nt*4 + r
      red[wave][r][lane]      = a00[r];
      red[wave][4 + r][lane]  = a01[r];
      red[wave][8 + r][lane]  = a10[r];
      red[wave][12 + r][lane] = a11[r];
    }
    __syncthreads();
    {
      short4v hv;
#pragma unroll
      for (int j = 0; j < 4; ++j) {
        const int nn   = nl + j;
        const int lidx = ((ml >> 2) & 3) * 16 + (nn & 15);   // C layout: lane=(row>>2)*16+col
        const int ridx = (ml >> 4) * 8 + (nn >> 4) * 4 + (ml & 3);
        float s = red[0][ridx][lidx] + red[1][ridx][lidx]
                + red[2][ridx][lidx] + red[3][ridx][lidx];
        s += b1r[j];
        hv[j] = f2bf(fabsf(s));
      }
      union { short4v s; u64 u; } hu; hu.s = hv;
      ast64(hb + (size_t)mrow * WID + (n0 + nl), hu.u);
    }
    __syncthreads();   // all 4 waves' h stores drained (vmcnt0) before signal
    if (tid == 0)
      __hip_atomic_store(hgen + chunk * 16, (unsigned)t + 1,
                         __ATOMIC_RELAXED, __HIP_MEMORY_SCOPE_AGENT);

    // ================= phase 2: g = h @ W2^T ; state update =================
    {  // wait: this wave's 16 h-producers (>= t+1); sticky per-lane poll
      const unsigned tgt = (unsigned)t + 1;
      bool pend = (lane < 16);
      for (;;) {
        if (pend && ald32(p2fp) >= tgt) pend = false;
        if (__ballot(pend) == 0ull) break;
        __builtin_amdgcn_s_sleep(1);
      }
    }
    f32x4 c00{}, c01{}, c10{}, c11{};
    {
      const short* h0 = hb + (size_t)m0 * WID + (kb + q8);
      const short* h1 = hb + (size_t)m1 * WID + (kb + q8);
#pragma unroll
      for (int ks = 0; ks < 16; ++ks) {
        short8 x0 = ald_s8(h0 + ks * 32);    // LLC-direct coherent read
        short8 x1 = ald_s8(h1 + ks * 32);
        c00 = __builtin_amdgcn_mfma_f32_16x16x32_bf16(x0, B2[ks][0], c00, 0, 0, 0);
        c01 = __builtin_amdgcn_mfma_f32_16x16x32_bf16(x0, B2[ks][1], c01, 0, 0, 0);
        c10 = __builtin_amdgcn_mfma_f32_16x16x32_bf16(x1, B2[ks][0], c10, 0, 0, 0);
        c11 = __builtin_amdgcn_mfma_f32_16x16x32_bf16(x1, B2[ks][1], c11, 0, 0, 0);
      }
    }
#pragma unroll
    for (int r = 0; r < 4; ++r) {
      red[wave][r][lane]      = c00[r];
      red[wave][4 + r][lane]  = c01[r];
      red[wave][8 + r][lane]  = c10[r];
      red[wave][12 + r][lane] = c11[r];
    }
    __syncthreads();
    if (t < NSTEPS - 1) {
      if (n0 < SS) {   // cols >= SS are dropped by the shift (except final step)
        f32x4 gv;
#pragma unroll
        for (int j = 0; j < 4; ++j) {
          const int nn   = nl + j;
          const int lidx = ((ml >> 2) & 3) * 16 + (nn & 15);
          const int ridx = (ml >> 4) * 8 + (nn >> 4) * 4 + (ml & 3);
          gv[j] = red[0][ridx][lidx] + red[1][ridx][lidx]
                + red[2][ridx][lidx] + red[3][ridx][lidx] + b2r[j];
        }
        f32x4 sv; short4v sb;
#pragma unroll
        for (int j = 0; j < 4; ++j) {
          float vv = 0.9f * prevv[j] + 0.1f * gv[j];
          sv[j] = vv; sb[j] = f2bf(vv);
        }
        union { f32x4 f; u64 u[2]; } sfu; sfu.f = sv;
        float* pf = SfNew + (size_t)mrow * SS + c0;
        ast64(pf, sfu.u[0]);
        ast64(pf + 2, sfu.u[1]);
        union { short4v s; u64 u; } sbu; sbu.s = sb;
        ast64(SbNew + (size_t)mrow * SS + c0, sbu.u);
      }
      __syncthreads();   // all 4 waves' S stores drained before signal
      if (tid == 0 && chunk < 62)
        __hip_atomic_store(sgen + chunk * 16, (unsigned)t + 1,
                           __ATOMIC_RELAXED, __HIP_MEMORY_SCOPE_AGENT);
    } else {
      // final step: out[m, :] = 0.9*s_in[m, 1984+o] + 0.1*(g+b2)[m, 1984+o]
      if (n0 >= SS) {
        f32x4 gv;
#pragma unroll
        for (int j = 0; j < 4; ++j) {
          const int nn   = nl + j;
          const int lidx = ((ml >> 2) & 3) * 16 + (nn & 15);
          const int ridx = (ml >> 4) * 8 + (nn >> 4) * 4 + (ml & 3);
          gv[j] = red[0][ridx][lidx] + red[1][ridx][lidx]
                + red[2][ridx][lidx] + red[3][ridx][lidx] + b2r[j];
        }
        f32x4 ov;
#pragma unroll
        for (int j = 0; j < 4; ++j) ov[j] = 0.9f * prevv[j] + 0.1f * gv[j];
        *(f32x4*)(out + (size_t)mrow * 64 + (c0 - SS)) = ov;
      }
    }
  }
}

extern "C" void kernel_launch(void* const* d_in, const int* in_sizes, int n_in,
                              void* d_out, int out_size, void* d_ws, size_t ws_size,
                              hipStream_t stream)
{
  (void)in_sizes; (void)n_in; (void)out_size; (void)ws_size;
  const float* inp = (const float*)d_in[0];
  const float* W1  = (const float*)d_in[1];
  const float* b1  = (const float*)d_in[2];
  const float* W2  = (const float*)d_in[3];
  const float* b2  = (const float*)d_in[4];
  float* out = (float*)d_out;

  // zero the flag area (ws is re-poisoned to 0xAA before every timed launch)
  hipMemsetAsync(d_ws, 0, 32768, stream);
  resrnn_kernel<<<dim3(256), dim3(256), 0, stream>>>(
      inp, W1, b1, W2, b2, out, (unsigned char*)d_ws);
}

// Round 5
// 2385.497 us; speedup vs baseline: 1.5739x; 1.0356x over previous
//
#include <hip/hip_runtime.h>
#include <stdint.h>

// ResRnn: T=128 sequential steps of  h=|s@W1^T+b1|; s'=0.9*shift(s)+0.1*(h@W2^T+b2)
// Persistent kernel: 256 WGs (1/CU), 4 independent batch-groups of 64 WGs,
// bf16 weights resident in VGPRs as MFMA B-frags.
// R6 protocol (proven 2425us): per-chunk monotone gen flags, 64B-strided slots,
//     tid0 store AFTER __syncthreads; relaxed agent-scope (sc1) data movement.
// R7 REVERTED (packed flags + atomic counters: 3180us, RMW contention).
// R8 REVERTED (acquire-fence + cached loads: 3754us, L2 invalidate thrash).
// R9 neutral (prevv hoist + sticky poll: 2470us ~ baseline) — kept (harmless,
//     hoist removes one exposed RT in principle; sticky poll cuts tail loads).
// R11 (this round): BURST-SPREADING software pipeline, consumer-side only.
//   Insight: each phase is a de-facto GROUP-WIDE convergence (union of the 4
//   waves' producer sets = all chunks), after which all 1024 waves fire ~33MB
//   of MALL line-requests in a ~1us burst -> queue spike -> tail latency ->
//   next convergence inherits max-of-64 tails. ~90% of time is waiting.
//   Fix: split each phase's 16-ks K-loop into 4 blocks of 4 ks. Per block:
//   wait only that block's 4 producer flags, issue its 8 loads, and compute
//   the PREVIOUS block's 16 MFMAs while the new loads (and the next flag
//   polls) are in flight. Early producers' data is consumed while stragglers
//   finish; the read burst spreads over the producer-completion window.
//   Flags/stores/barriers/signaling byte-identical to R6. Macros with literal
//   block indices keep all register arrays statically indexed (rule #20).
// Buffer safety unchanged: S ping-pong + single h buffer.

#define NSTEPS 128
#define NB 128
#define WID 2048
#define SS 1984   // recurrent state width (WIDTH - INPUT_SIZE)

typedef __attribute__((ext_vector_type(8))) short short8;
typedef __attribute__((ext_vector_type(4))) short short4v;
typedef __attribute__((ext_vector_type(4))) float f32x4;
typedef unsigned long long u64;

static __device__ __forceinline__ short f2bf(float f) {
  union { float f; unsigned u; } v; v.f = f;
  unsigned r = (v.u + 0x7fffu + ((v.u >> 16) & 1u)) >> 16;  // RNE
  return (short)r;
}

static __device__ __forceinline__ short8 pack8(f32x4 lo, f32x4 hi) {
  short8 r;
  r[0] = f2bf(lo[0]); r[1] = f2bf(lo[1]); r[2] = f2bf(lo[2]); r[3] = f2bf(lo[3]);
  r[4] = f2bf(hi[0]); r[5] = f2bf(hi[1]); r[6] = f2bf(hi[2]); r[7] = f2bf(hi[3]);
  return r;
}

// write-through store to the agent coherence point (LLC); does not dirty L2
static __device__ __forceinline__ void ast64(void* p, u64 v) {
  __hip_atomic_store((u64*)p, v, __ATOMIC_RELAXED, __HIP_MEMORY_SCOPE_AGENT);
}
// LLC-direct coherent loads (bypass possibly-stale L1/L2)
static __device__ __forceinline__ u64 ald64(const void* p) {
  return __hip_atomic_load((const u64*)p, __ATOMIC_RELAXED, __HIP_MEMORY_SCOPE_AGENT);
}
static __device__ __forceinline__ unsigned ald32(const unsigned* p) {
  return __hip_atomic_load(p, __ATOMIC_RELAXED, __HIP_MEMORY_SCOPE_AGENT);
}
static __device__ __forceinline__ short8 ald_s8(const void* p) {
  union { u64 u[2]; short8 s; } r;
  r.u[0] = ald64((const char*)p);
  r.u[1] = ald64((const char*)p + 8);
  return r.s;
}
static __device__ __forceinline__ f32x4 ald_f4(const void* p) {
  union { u64 u[2]; f32x4 f; } r;
  r.u[0] = ald64((const char*)p);
  r.u[1] = ald64((const char*)p + 8);
  return r.f;
}

// ---- phase-1 pipeline macros (literal b: static reg indexing, rule #20) ----
// wait: lanes 0..3 poll sgen for producer 16w+4b+lane-2 (pc<0 -> input, no wait);
//       b==0 additionally: lane 16 polls sgen[chunk-2] (covers hoisted prevv).
#define P1WAIT(b) do {                                                        \
    const int pc_ = 16 * wave + 4 * (b) + (lane & 3) - 2;                     \
    bool pend_; const unsigned* fp_;                                          \
    if (lane < 4 && pc_ >= 0)            { pend_ = true; fp_ = sgen + pc_ * 16; } \
    else if ((b) == 0 && lane == 16 && chunk >= 2)                            \
                                         { pend_ = true; fp_ = sgen + (chunk - 2) * 16; } \
    else                                 { pend_ = false; fp_ = sgen; }       \
    const unsigned tg_ = (unsigned)t;                                         \
    for (;;) {                                                                \
      if (pend_ && ald32(fp_) >= tg_) pend_ = false;                          \
      if (__ballot(pend_) == 0ull) break;                                     \
      __builtin_amdgcn_s_sleep(1);                                            \
    }                                                                         \
  } while (0)

#define P1LOAD(b, X) do {                                                     \
    if (kb == 0 && (b) == 0) {  /* ks 0,1 = x_t input; ks 2,3 = Sb cols 0,32 */ \
      const float* q0_ = inp + ((size_t)t * NB + m0) * 64 + q8;               \
      const float* q1_ = inp + ((size_t)t * NB + m1) * 64 + q8;               \
      X[0] = pack8(*(const f32x4*)q0_, *(const f32x4*)(q0_ + 4));             \
      X[1] = pack8(*(const f32x4*)q1_, *(const f32x4*)(q1_ + 4));             \
      X[2] = pack8(*(const f32x4*)(q0_ + 32), *(const f32x4*)(q0_ + 36));     \
      X[3] = pack8(*(const f32x4*)(q1_ + 32), *(const f32x4*)(q1_ + 36));     \
      X[4] = ald_s8(SbOld + (size_t)m0 * SS + q8);                            \
      X[5] = ald_s8(SbOld + (size_t)m1 * SS + q8);                            \
      X[6] = ald_s8(SbOld + (size_t)m0 * SS + 32 + q8);                       \
      X[7] = ald_s8(SbOld + (size_t)m1 * SS + 32 + q8);                       \
    } else {                                                                  \
      const short* s0_ = SbOld + (size_t)m0 * SS + (kb + 4 * (b) * 32 - 64 + q8); \
      const short* s1_ = SbOld + (size_t)m1 * SS + (kb + 4 * (b) * 32 - 64 + q8); \
      X[0] = ald_s8(s0_);      X[1] = ald_s8(s1_);                            \
      X[2] = ald_s8(s0_ + 32); X[3] = ald_s8(s1_ + 32);                       \
      X[4] = ald_s8(s0_ + 64); X[5] = ald_s8(s1_ + 64);                       \
      X[6] = ald_s8(s0_ + 96); X[7] = ald_s8(s1_ + 96);                       \
    }                                                                         \
  } while (0)

#define P1MFMA(b, X) do {                                                     \
    a00 = __builtin_amdgcn_mfma_f32_16x16x32_bf16(X[0], B1[4*(b)+0][0], a00, 0,0,0); \
    a01 = __builtin_amdgcn_mfma_f32_16x16x32_bf16(X[0], B1[4*(b)+0][1], a01, 0,0,0); \
    a10 = __builtin_amdgcn_mfma_f32_16x16x32_bf16(X[1], B1[4*(b)+0][0], a10, 0,0,0); \
    a11 = __builtin_amdgcn_mfma_f32_16x16x32_bf16(X[1], B1[4*(b)+0][1], a11, 0,0,0); \
    a00 = __builtin_amdgcn_mfma_f32_16x16x32_bf16(X[2], B1[4*(b)+1][0], a00, 0,0,0); \
    a01 = __builtin_amdgcn_mfma_f32_16x16x32_bf16(X[2], B1[4*(b)+1][1], a01, 0,0,0); \
    a10 = __builtin_amdgcn_mfma_f32_16x16x32_bf16(X[3], B1[4*(b)+1][0], a10, 0,0,0); \
    a11 = __builtin_amdgcn_mfma_f32_16x16x32_bf16(X[3], B1[4*(b)+1][1], a11, 0,0,0); \
    a00 = __builtin_amdgcn_mfma_f32_16x16x32_bf16(X[4], B1[4*(b)+2][0], a00, 0,0,0); \
    a01 = __builtin_amdgcn_mfma_f32_16x16x32_bf16(X[4], B1[4*(b)+2][1], a01, 0,0,0); \
    a10 = __builtin_amdgcn_mfma_f32_16x16x32_bf16(X[5], B1[4*(b)+2][0], a10, 0,0,0); \
    a11 = __builtin_amdgcn_mfma_f32_16x16x32_bf16(X[5], B1[4*(b)+2][1], a11, 0,0,0); \
    a00 = __builtin_amdgcn_mfma_f32_16x16x32_bf16(X[6], B1[4*(b)+3][0], a00, 0,0,0); \
    a01 = __builtin_amdgcn_mfma_f32_16x16x32_bf16(X[6], B1[4*(b)+3][1], a01, 0,0,0); \
    a10 = __builtin_amdgcn_mfma_f32_16x16x32_bf16(X[7], B1[4*(b)+3][0], a10, 0,0,0); \
    a11 = __builtin_amdgcn_mfma_f32_16x16x32_bf16(X[7], B1[4*(b)+3][1], a11, 0,0,0); \
  } while (0)

// ---- phase-2 pipeline macros: producers hgen[16w+4b+lane], target t+1 ----
#define P2WAIT(b) do {                                                        \
    bool pend_ = (lane < 4);                                                  \
    const unsigned* fp_ = hgen + (16 * wave + 4 * (b) + (lane & 3)) * 16;     \
    const unsigned tg_ = (unsigned)t + 1;                                     \
    for (;;) {                                                                \
      if (pend_ && ald32(fp_) >= tg_) pend_ = false;                          \
      if (__ballot(pend_) == 0ull) break;                                     \
      __builtin_amdgcn_s_sleep(1);                                            \
    }                                                                         \
  } while (0)

#define P2LOAD(b, X) do {                                                     \
    X[0] = ald_s8(h0 + (4*(b)+0) * 32); X[1] = ald_s8(h1 + (4*(b)+0) * 32);   \
    X[2] = ald_s8(h0 + (4*(b)+1) * 32); X[3] = ald_s8(h1 + (4*(b)+1) * 32);   \
    X[4] = ald_s8(h0 + (4*(b)+2) * 32); X[5] = ald_s8(h1 + (4*(b)+2) * 32);   \
    X[6] = ald_s8(h0 + (4*(b)+3) * 32); X[7] = ald_s8(h1 + (4*(b)+3) * 32);   \
  } while (0)

#define P2MFMA(b, X) do {                                                     \
    c00 = __builtin_amdgcn_mfma_f32_16x16x32_bf16(X[0], B2[4*(b)+0][0], c00, 0,0,0); \
    c01 = __builtin_amdgcn_mfma_f32_16x16x32_bf16(X[0], B2[4*(b)+0][1], c01, 0,0,0); \
    c10 = __builtin_amdgcn_mfma_f32_16x16x32_bf16(X[1], B2[4*(b)+0][0], c10, 0,0,0); \
    c11 = __builtin_amdgcn_mfma_f32_16x16x32_bf16(X[1], B2[4*(b)+0][1], c11, 0,0,0); \
    c00 = __builtin_amdgcn_mfma_f32_16x16x32_bf16(X[2], B2[4*(b)+1][0], c00, 0,0,0); \
    c01 = __builtin_amdgcn_mfma_f32_16x16x32_bf16(X[2], B2[4*(b)+1][1], c01, 0,0,0); \
    c10 = __builtin_amdgcn_mfma_f32_16x16x32_bf16(X[3], B2[4*(b)+1][0], c10, 0,0,0); \
    c11 = __builtin_amdgcn_mfma_f32_16x16x32_bf16(X[3], B2[4*(b)+1][1], c11, 0,0,0); \
    c00 = __builtin_amdgcn_mfma_f32_16x16x32_bf16(X[4], B2[4*(b)+2][0], c00, 0,0,0); \
    c01 = __builtin_amdgcn_mfma_f32_16x16x32_bf16(X[4], B2[4*(b)+2][1], c01, 0,0,0); \
    c10 = __builtin_amdgcn_mfma_f32_16x16x32_bf16(X[5], B2[4*(b)+2][0], c10, 0,0,0); \
    c11 = __builtin_amdgcn_mfma_f32_16x16x32_bf16(X[5], B2[4*(b)+2][1], c11, 0,0,0); \
    c00 = __builtin_amdgcn_mfma_f32_16x16x32_bf16(X[6], B2[4*(b)+3][0], c00, 0,0,0); \
    c01 = __builtin_amdgcn_mfma_f32_16x16x32_bf16(X[6], B2[4*(b)+3][1], c01, 0,0,0); \
    c10 = __builtin_amdgcn_mfma_f32_16x16x32_bf16(X[7], B2[4*(b)+3][0], c10, 0,0,0); \
    c11 = __builtin_amdgcn_mfma_f32_16x16x32_bf16(X[7], B2[4*(b)+3][1], c11, 0,0,0); \
  } while (0)

__global__ __launch_bounds__(256, 1)
void resrnn_kernel(const float* __restrict__ inp, const float* __restrict__ W1,
                   const float* __restrict__ b1f, const float* __restrict__ W2,
                   const float* __restrict__ b2f, float* __restrict__ out,
                   unsigned char* __restrict__ ws)
{
  const int tid   = threadIdx.x;
  const int bid   = blockIdx.x;
  const int group = bid & 3;        // 4 independent batch groups (32 rows each)
  const int chunk = bid >> 2;       // 64 N-chunks of 32 cols
  const int mbase = group * 32;
  const int n0    = chunk * 32;
  const int wave  = tid >> 6;
  const int lane  = tid & 63;
  const int l15   = lane & 15;
  const int q8    = (lane >> 4) * 8;
  const int kb    = wave * 512;     // K split 4 ways across waves

  // per-group flag arrays: 64 chunks x 64B slots (16 u32 stride), monotone gens
  unsigned* sgen = (unsigned*)(ws + group * 8192);          // S-chunk ready: value t+1
  unsigned* hgen = (unsigned*)(ws + group * 8192 + 4096);   // h-chunk ready: value t+1
  float* Sf0 = (float*)(ws + 32768);                 // fp32 state master, ping
  float* Sf1 = (float*)(ws + 32768 + 1015808);       // pong
  short* Sb0 = (short*)(ws + 32768 + 2031616);       // bf16 state, ping
  short* Sb1 = (short*)(ws + 32768 + 2539520);       // pong
  short* hb  = (short*)(ws + 32768 + 3047424);       // bf16 h buffer [128][2048]

  __shared__ float red[4][16][65];  // +1 pad: conflict-free cross-wave reduce

  // ---- one-time: load & convert weight B-fragments into registers ----
  // B-frag layout (verified m89): n = lane&15 (row of W), k = (lane>>4)*8+j contiguous
  short8 B1[16][2], B2[16][2];
#pragma unroll
  for (int ks = 0; ks < 16; ++ks) {
#pragma unroll
    for (int nt = 0; nt < 2; ++nt) {
      const float* p1 = W1 + (size_t)(n0 + nt * 16 + l15) * WID + (kb + ks * 32 + q8);
      B1[ks][nt] = pack8(*(const f32x4*)p1, *(const f32x4*)(p1 + 4));
      const float* p2 = W2 + (size_t)(n0 + nt * 16 + l15) * WID + (kb + ks * 32 + q8);
      B2[ks][nt] = pack8(*(const f32x4*)p2, *(const f32x4*)(p2 + 4));
    }
  }

  const int m0 = mbase + l15;        // A-frag rows (m-tile 0)
  const int m1 = mbase + 16 + l15;   // m-tile 1

  const int o    = tid * 4;          // epilogue: 4 outputs per thread of 32x32 tile
  const int ml   = o >> 5;
  const int nl   = o & 31;
  const int mrow = mbase + ml;
  const int c0   = n0 + nl;          // this thread's absolute output column

  // biases for this thread's 4 output columns, loaded once (constant over t)
  const f32x4 b1r = *(const f32x4*)(b1f + n0 + nl);
  const f32x4 b2r = *(const f32x4*)(b2f + n0 + nl);

  short8 xa[8], xb[8];   // double-buffered in-flight operand blocks

#pragma unroll 1
  for (int t = 0; t < NSTEPS; ++t) {
    const float* SfOld = (t & 1) ? Sf1 : Sf0;
    float*       SfNew = (t & 1) ? Sf0 : Sf1;
    const short* SbOld = (t & 1) ? Sb1 : Sb0;
    short*       SbNew = (t & 1) ? Sb0 : Sb1;

    // ================= phase 1: u = s_in @ W1^T ; h = |u + b1| =================
    f32x4 a00{}, a01{}, a10{}, a11{};
    f32x4 prevv;
    if (t == 0) {
      // state is zero: only the x_t part contributes (wave 0, ks 0..1)
      prevv = (c0 < 64) ? *(const f32x4*)(inp + (size_t)mrow * 64 + c0)
                        : f32x4{0.f, 0.f, 0.f, 0.f};
      if (kb == 0) {
        const float* q0_ = inp + (size_t)m0 * 64 + q8;
        const float* q1_ = inp + (size_t)m1 * 64 + q8;
        short8 x0 = pack8(*(const f32x4*)q0_, *(const f32x4*)(q0_ + 4));
        short8 x1 = pack8(*(const f32x4*)q1_, *(const f32x4*)(q1_ + 4));
        short8 x2 = pack8(*(const f32x4*)(q0_ + 32), *(const f32x4*)(q0_ + 36));
        short8 x3 = pack8(*(const f32x4*)(q1_ + 32), *(const f32x4*)(q1_ + 36));
        a00 = __builtin_amdgcn_mfma_f32_16x16x32_bf16(x0, B1[0][0], a00, 0, 0, 0);
        a01 = __builtin_amdgcn_mfma_f32_16x16x32_bf16(x0, B1[0][1], a01, 0, 0, 0);
        a10 = __builtin_amdgcn_mfma_f32_16x16x32_bf16(x1, B1[0][0], a10, 0, 0, 0);
        a11 = __builtin_amdgcn_mfma_f32_16x16x32_bf16(x1, B1[0][1], a11, 0, 0, 0);
        a00 = __builtin_amdgcn_mfma_f32_16x16x32_bf16(x2, B1[1][0], a00, 0, 0, 0);
        a01 = __builtin_amdgcn_mfma_f32_16x16x32_bf16(x2, B1[1][1], a01, 0, 0, 0);
        a10 = __builtin_amdgcn_mfma_f32_16x16x32_bf16(x3, B1[1][0], a10, 0, 0, 0);
        a11 = __builtin_amdgcn_mfma_f32_16x16x32_bf16(x3, B1[1][1], a11, 0, 0, 0);
      }
    } else {
      // 4-block pipelined: wait(b)/load(b) overlap MFMA(b-1)
      P1WAIT(0);
      // hoisted epilogue prev (producer chunk-2 covered by P1WAIT(0) lane 16)
      if (c0 < 64) prevv = *(const f32x4*)(inp + ((size_t)t * NB + mrow) * 64 + c0);
      else         prevv = ald_f4(SfOld + (size_t)mrow * SS + (c0 - 64));
      P1LOAD(0, xa);
      P1WAIT(1); P1LOAD(1, xb); P1MFMA(0, xa);
      P1WAIT(2); P1LOAD(2, xa); P1MFMA(1, xb);
      P1WAIT(3); P1LOAD(3, xb); P1MFMA(2, xa);
      P1MFMA(3, xb);
    }
#pragma unroll
    for (int r = 0; r < 4; ++r) {            // ridx = mt*8 + nt*4 + r
      red[wave][r][lane]      = a00[r];
      red[wave][4 + r][lane]  = a01[r];
      red[wave][8 + r][lane]  = a10[r];
      red[wave][12 + r][lane] = a11[r];
    }
    __syncthreads();
    {
      short4v hv;
#pragma unroll
      for (int j = 0; j < 4; ++j) {
        const int nn   = nl + j;
        const int lidx = ((ml >> 2) & 3) * 16 + (nn & 15);   // C layout: lane=(row>>2)*16+col
        const int ridx = (ml >> 4) * 8 + (nn >> 4) * 4 + (ml & 3);
        float s = red[0][ridx][lidx] + red[1][ridx][lidx]
                + red[2][ridx][lidx] + red[3][ridx][lidx];
        s += b1r[j];
        hv[j] = f2bf(fabsf(s));
      }
      union { short4v s; u64 u; } hu; hu.s = hv;
      ast64(hb + (size_t)mrow * WID + (n0 + nl), hu.u);
    }
    __syncthreads();   // all 4 waves' h stores drained (vmcnt0) before signal
    if (tid == 0)
      __hip_atomic_store(hgen + chunk * 16, (unsigned)t + 1,
                         __ATOMIC_RELAXED, __HIP_MEMORY_SCOPE_AGENT);

    // ================= phase 2: g = h @ W2^T ; state update =================
    f32x4 c00{}, c01{}, c10{}, c11{};
    {
      const short* h0 = hb + (size_t)m0 * WID + (kb + q8);
      const short* h1 = hb + (size_t)m1 * WID + (kb + q8);
      P2WAIT(0); P2LOAD(0, xa);
      P2WAIT(1); P2LOAD(1, xb); P2MFMA(0, xa);
      P2WAIT(2); P2LOAD(2, xa); P2MFMA(1, xb);
      P2WAIT(3); P2LOAD(3, xb); P2MFMA(2, xa);
      P2MFMA(3, xb);
    }
#pragma unroll
    for (int r = 0; r < 4; ++r) {
      red[wave][r][lane]      = c00[r];
      red[wave][4 + r][lane]  = c01[r];
      red[wave][8 + r][lane]  = c10[r];
      red[wave][12 + r][lane] = c11[r];
    }
    __syncthreads();
    if (t < NSTEPS - 1) {
      if (n0 < SS) {   // cols >= SS are dropped by the shift (except final step)
        f32x4 gv;
#pragma unroll
        for (int j = 0; j < 4; ++j) {
          const int nn   = nl + j;
          const int lidx = ((ml >> 2) & 3) * 16 + (nn & 15);
          const int ridx = (ml >> 4) * 8 + (nn >> 4) * 4 + (ml & 3);
          gv[j] = red[0][ridx][lidx] + red[1][ridx][lidx]
                + red[2][ridx][lidx] + red[3][ridx][lidx] + b2r[j];
        }
        f32x4 sv; short4v sb;
#pragma unroll
        for (int j = 0; j < 4; ++j) {
          float vv = 0.9f * prevv[j] + 0.1f * gv[j];
          sv[j] = vv; sb[j] = f2bf(vv);
        }
        union { f32x4 f; u64 u[2]; } sfu; sfu.f = sv;
        float* pf = SfNew + (size_t)mrow * SS + c0;
        ast64(pf, sfu.u[0]);
        ast64(pf + 2, sfu.u[1]);
        union { short4v s; u64 u; } sbu; sbu.s = sb;
        ast64(SbNew + (size_t)mrow * SS + c0, sbu.u);
      }
      __syncthreads();   // all 4 waves' S stores drained before signal
      if (tid == 0 && chunk < 62)
        __hip_atomic_store(sgen + chunk * 16, (unsigned)t + 1,
                           __ATOMIC_RELAXED, __HIP_MEMORY_SCOPE_AGENT);
    } else {
      // final step: out[m, :] = 0.9*s_in[m, 1984+o] + 0.1*(g+b2)[m, 1984+o]
      if (n0 >= SS) {
        f32x4 gv;
#pragma unroll
        for (int j = 0; j < 4; ++j) {
          const int nn   = nl + j;
          const int lidx = ((ml >> 2) & 3) * 16 + (nn & 15);
          const int ridx = (ml >> 4) * 8 + (nn >> 4) * 4 + (ml & 3);
          gv[j] = red[0][ridx][lidx] + red[1][ridx][lidx]
                + red[2][ridx][lidx] + red[3][ridx][lidx] + b2r[j];
        }
        f32x4 ov;
#pragma unroll
        for (int j = 0; j < 4; ++j) ov[j] = 0.9f * prevv[j] + 0.1f * gv[j];
        *(f32x4*)(out + (size_t)mrow * 64 + (c0 - SS)) = ov;
      }
    }
  }
}

extern "C" void kernel_launch(void* const* d_in, const int* in_sizes, int n_in,
                              void* d_out, int out_size, void* d_ws, size_t ws_size,
                              hipStream_t stream)
{
  (void)in_sizes; (void)n_in; (void)out_size; (void)ws_size;
  const float* inp = (const float*)d_in[0];
  const float* W1  = (const float*)d_in[1];
  const float* b1  = (const float*)d_in[2];
  const float* W2  = (const float*)d_in[3];
  const float* b2  = (const float*)d_in[4];
  float* out = (float*)d_out;

  // zero the flag area (ws is re-poisoned to 0xAA before every timed launch)
  hipMemsetAsync(d_ws, 0, 32768, stream);
  resrnn_kernel<<<dim3(256), dim3(256), 0, stream>>>(
      inp, W1, b1, W2, b2, out, (unsigned char*)d_ws);
}

// Round 7
// 2376.779 us; speedup vs baseline: 1.5797x; 1.0037x over previous
//
#include <hip/hip_runtime.h>
#include <stdint.h>

// ResRnn: T=128 sequential steps of  h=|s@W1^T+b1|; s'=0.9*shift(s)+0.1*(h@W2^T+b2)
// Persistent kernel: 256 WGs (1/CU), 4 independent batch-groups of 64 WGs,
// bf16 weights resident in VGPRs as MFMA B-frags.
// R6 protocol (proven 2425us): per-chunk monotone gen flags, 64B-strided slots,
//     tid0 store AFTER __syncthreads; relaxed agent-scope (sc1) data movement.
// R7 REVERTED (packed flags + atomic counters: 3180us, RMW contention).
// R8 REVERTED (acquire-fence + cached loads: 3754us, L2 invalidate thrash).
// R9 neutral-kept (prevv hoist + sticky poll: ~baseline).
// R11 (2385us, passed): 4-block burst-spread pipeline per phase — kept.
// R12 REVERTED (u-space rewrite: MATH WRONG — concat is a SHIFT, so
//     u_{t+1} needs W1[:,64:]·s_in[0:1984] (shifted alignment), which is not
//     expressible via u_t without W1^-1. 2 matmuls + 2 convergences per step
//     are structural. absmax 0.31 confirmed.)
// R13 (this round, single delta): BUSY-SPIN polls — s_sleep removed from both
//     wait macros. Theory: effective clock back-computed from MfmaUtil is
//     ~765MHz (640 MFMA-cy/step / 4.5% = 14.2k cy/step over 18.6us); s_sleep
//     in the dominant poll stalls hints idleness to power mgmt -> downclock.
//     Busy-spin keeps issue activity up and removes backoff quantization.
//     Poll volume returns to ~R6 levels (proven non-binding by R7/R9).
// Buffer safety unchanged: S ping-pong + single h buffer.

#define NSTEPS 128
#define NB 128
#define WID 2048
#define SS 1984   // recurrent state width (WIDTH - INPUT_SIZE)

typedef __attribute__((ext_vector_type(8))) short short8;
typedef __attribute__((ext_vector_type(4))) short short4v;
typedef __attribute__((ext_vector_type(4))) float f32x4;
typedef unsigned long long u64;

static __device__ __forceinline__ short f2bf(float f) {
  union { float f; unsigned u; } v; v.f = f;
  unsigned r = (v.u + 0x7fffu + ((v.u >> 16) & 1u)) >> 16;  // RNE
  return (short)r;
}

static __device__ __forceinline__ short8 pack8(f32x4 lo, f32x4 hi) {
  short8 r;
  r[0] = f2bf(lo[0]); r[1] = f2bf(lo[1]); r[2] = f2bf(lo[2]); r[3] = f2bf(lo[3]);
  r[4] = f2bf(hi[0]); r[5] = f2bf(hi[1]); r[6] = f2bf(hi[2]); r[7] = f2bf(hi[3]);
  return r;
}

// write-through store to the agent coherence point (LLC); does not dirty L2
static __device__ __forceinline__ void ast64(void* p, u64 v) {
  __hip_atomic_store((u64*)p, v, __ATOMIC_RELAXED, __HIP_MEMORY_SCOPE_AGENT);
}
// LLC-direct coherent loads (bypass possibly-stale L1/L2)
static __device__ __forceinline__ u64 ald64(const void* p) {
  return __hip_atomic_load((const u64*)p, __ATOMIC_RELAXED, __HIP_MEMORY_SCOPE_AGENT);
}
static __device__ __forceinline__ unsigned ald32(const unsigned* p) {
  return __hip_atomic_load(p, __ATOMIC_RELAXED, __HIP_MEMORY_SCOPE_AGENT);
}
static __device__ __forceinline__ short8 ald_s8(const void* p) {
  union { u64 u[2]; short8 s; } r;
  r.u[0] = ald64((const char*)p);
  r.u[1] = ald64((const char*)p + 8);
  return r.s;
}
static __device__ __forceinline__ f32x4 ald_f4(const void* p) {
  union { u64 u[2]; f32x4 f; } r;
  r.u[0] = ald64((const char*)p);
  r.u[1] = ald64((const char*)p + 8);
  return r.f;
}

// ---- phase-1 pipeline macros (literal b: static reg indexing, rule #20) ----
// wait: lanes 0..3 poll sgen for producer 16w+4b+lane-2 (pc<0 -> input, no wait);
//       b==0 additionally: lane 16 polls sgen[chunk-2] (covers hoisted prevv).
// BUSY-SPIN (R13): no s_sleep backoff.
#define P1WAIT(b) do {                                                        \
    const int pc_ = 16 * wave + 4 * (b) + (lane & 3) - 2;                     \
    bool pend_; const unsigned* fp_;                                          \
    if (lane < 4 && pc_ >= 0)            { pend_ = true; fp_ = sgen + pc_ * 16; } \
    else if ((b) == 0 && lane == 16 && chunk >= 2)                            \
                                         { pend_ = true; fp_ = sgen + (chunk - 2) * 16; } \
    else                                 { pend_ = false; fp_ = sgen; }       \
    const unsigned tg_ = (unsigned)t;                                         \
    for (;;) {                                                                \
      if (pend_ && ald32(fp_) >= tg_) pend_ = false;                          \
      if (__ballot(pend_) == 0ull) break;                                     \
    }                                                                         \
  } while (0)

#define P1LOAD(b, X) do {                                                     \
    if (kb == 0 && (b) == 0) {  /* ks 0,1 = x_t input; ks 2,3 = Sb cols 0,32 */ \
      const float* q0_ = inp + ((size_t)t * NB + m0) * 64 + q8;               \
      const float* q1_ = inp + ((size_t)t * NB + m1) * 64 + q8;               \
      X[0] = pack8(*(const f32x4*)q0_, *(const f32x4*)(q0_ + 4));             \
      X[1] = pack8(*(const f32x4*)q1_, *(const f32x4*)(q1_ + 4));             \
      X[2] = pack8(*(const f32x4*)(q0_ + 32), *(const f32x4*)(q0_ + 36));     \
      X[3] = pack8(*(const f32x4*)(q1_ + 32), *(const f32x4*)(q1_ + 36));     \
      X[4] = ald_s8(SbOld + (size_t)m0 * SS + q8);                            \
      X[5] = ald_s8(SbOld + (size_t)m1 * SS + q8);                            \
      X[6] = ald_s8(SbOld + (size_t)m0 * SS + 32 + q8);                       \
      X[7] = ald_s8(SbOld + (size_t)m1 * SS + 32 + q8);                       \
    } else {                                                                  \
      const short* s0_ = SbOld + (size_t)m0 * SS + (kb + 4 * (b) * 32 - 64 + q8); \
      const short* s1_ = SbOld + (size_t)m1 * SS + (kb + 4 * (b) * 32 - 64 + q8); \
      X[0] = ald_s8(s0_);      X[1] = ald_s8(s1_);                            \
      X[2] = ald_s8(s0_ + 32); X[3] = ald_s8(s1_ + 32);                       \
      X[4] = ald_s8(s0_ + 64); X[5] = ald_s8(s1_ + 64);                       \
      X[6] = ald_s8(s0_ + 96); X[7] = ald_s8(s1_ + 96);                       \
    }                                                                         \
  } while (0)

#define P1MFMA(b, X) do {                                                     \
    a00 = __builtin_amdgcn_mfma_f32_16x16x32_bf16(X[0], B1[4*(b)+0][0], a00, 0,0,0); \
    a01 = __builtin_amdgcn_mfma_f32_16x16x32_bf16(X[0], B1[4*(b)+0][1], a01, 0,0,0); \
    a10 = __builtin_amdgcn_mfma_f32_16x16x32_bf16(X[1], B1[4*(b)+0][0], a10, 0,0,0); \
    a11 = __builtin_amdgcn_mfma_f32_16x16x32_bf16(X[1], B1[4*(b)+0][1], a11, 0,0,0); \
    a00 = __builtin_amdgcn_mfma_f32_16x16x32_bf16(X[2], B1[4*(b)+1][0], a00, 0,0,0); \
    a01 = __builtin_amdgcn_mfma_f32_16x16x32_bf16(X[2], B1[4*(b)+1][1], a01, 0,0,0); \
    a10 = __builtin_amdgcn_mfma_f32_16x16x32_bf16(X[3], B1[4*(b)+1][0], a10, 0,0,0); \
    a11 = __builtin_amdgcn_mfma_f32_16x16x32_bf16(X[3], B1[4*(b)+1][1], a11, 0,0,0); \
    a00 = __builtin_amdgcn_mfma_f32_16x16x32_bf16(X[4], B1[4*(b)+2][0], a00, 0,0,0); \
    a01 = __builtin_amdgcn_mfma_f32_16x16x32_bf16(X[4], B1[4*(b)+2][1], a01, 0,0,0); \
    a10 = __builtin_amdgcn_mfma_f32_16x16x32_bf16(X[5], B1[4*(b)+2][0], a10, 0,0,0); \
    a11 = __builtin_amdgcn_mfma_f32_16x16x32_bf16(X[5], B1[4*(b)+2][1], a11, 0,0,0); \
    a00 = __builtin_amdgcn_mfma_f32_16x16x32_bf16(X[6], B1[4*(b)+3][0], a00, 0,0,0); \
    a01 = __builtin_amdgcn_mfma_f32_16x16x32_bf16(X[6], B1[4*(b)+3][1], a01, 0,0,0); \
    a10 = __builtin_amdgcn_mfma_f32_16x16x32_bf16(X[7], B1[4*(b)+3][0], a10, 0,0,0); \
    a11 = __builtin_amdgcn_mfma_f32_16x16x32_bf16(X[7], B1[4*(b)+3][1], a11, 0,0,0); \
  } while (0)

// ---- phase-2 pipeline macros: producers hgen[16w+4b+lane], target t+1 ----
#define P2WAIT(b) do {                                                        \
    bool pend_ = (lane < 4);                                                  \
    const unsigned* fp_ = hgen + (16 * wave + 4 * (b) + (lane & 3)) * 16;     \
    const unsigned tg_ = (unsigned)t + 1;                                     \
    for (;;) {                                                                \
      if (pend_ && ald32(fp_) >= tg_) pend_ = false;                          \
      if (__ballot(pend_) == 0ull) break;                                     \
    }                                                                         \
  } while (0)

#define P2LOAD(b, X) do {                                                     \
    X[0] = ald_s8(h0 + (4*(b)+0) * 32); X[1] = ald_s8(h1 + (4*(b)+0) * 32);   \
    X[2] = ald_s8(h0 + (4*(b)+1) * 32); X[3] = ald_s8(h1 + (4*(b)+1) * 32);   \
    X[4] = ald_s8(h0 + (4*(b)+2) * 32); X[5] = ald_s8(h1 + (4*(b)+2) * 32);   \
    X[6] = ald_s8(h0 + (4*(b)+3) * 32); X[7] = ald_s8(h1 + (4*(b)+3) * 32);   \
  } while (0)

#define P2MFMA(b, X) do {                                                     \
    c00 = __builtin_amdgcn_mfma_f32_16x16x32_bf16(X[0], B2[4*(b)+0][0], c00, 0,0,0); \
    c01 = __builtin_amdgcn_mfma_f32_16x16x32_bf16(X[0], B2[4*(b)+0][1], c01, 0,0,0); \
    c10 = __builtin_amdgcn_mfma_f32_16x16x32_bf16(X[1], B2[4*(b)+0][0], c10, 0,0,0); \
    c11 = __builtin_amdgcn_mfma_f32_16x16x32_bf16(X[1], B2[4*(b)+0][1], c11, 0,0,0); \
    c00 = __builtin_amdgcn_mfma_f32_16x16x32_bf16(X[2], B2[4*(b)+1][0], c00, 0,0,0); \
    c01 = __builtin_amdgcn_mfma_f32_16x16x32_bf16(X[2], B2[4*(b)+1][1], c01, 0,0,0); \
    c10 = __builtin_amdgcn_mfma_f32_16x16x32_bf16(X[3], B2[4*(b)+1][0], c10, 0,0,0); \
    c11 = __builtin_amdgcn_mfma_f32_16x16x32_bf16(X[3], B2[4*(b)+1][1], c11, 0,0,0); \
    c00 = __builtin_amdgcn_mfma_f32_16x16x32_bf16(X[4], B2[4*(b)+2][0], c00, 0,0,0); \
    c01 = __builtin_amdgcn_mfma_f32_16x16x32_bf16(X[4], B2[4*(b)+2][1], c01, 0,0,0); \
    c10 = __builtin_amdgcn_mfma_f32_16x16x32_bf16(X[5], B2[4*(b)+2][0], c10, 0,0,0); \
    c11 = __builtin_amdgcn_mfma_f32_16x16x32_bf16(X[5], B2[4*(b)+2][1], c11, 0,0,0); \
    c00 = __builtin_amdgcn_mfma_f32_16x16x32_bf16(X[6], B2[4*(b)+3][0], c00, 0,0,0); \
    c01 = __builtin_amdgcn_mfma_f32_16x16x32_bf16(X[6], B2[4*(b)+3][1], c01, 0,0,0); \
    c10 = __builtin_amdgcn_mfma_f32_16x16x32_bf16(X[7], B2[4*(b)+3][0], c10, 0,0,0); \
    c11 = __builtin_amdgcn_mfma_f32_16x16x32_bf16(X[7], B2[4*(b)+3][1], c11, 0,0,0); \
  } while (0)

__global__ __launch_bounds__(256, 1)
void resrnn_kernel(const float* __restrict__ inp, const float* __restrict__ W1,
                   const float* __restrict__ b1f, const float* __restrict__ W2,
                   const float* __restrict__ b2f, float* __restrict__ out,
                   unsigned char* __restrict__ ws)
{
  const int tid   = threadIdx.x;
  const int bid   = blockIdx.x;
  const int group = bid & 3;        // 4 independent batch groups (32 rows each)
  const int chunk = bid >> 2;       // 64 N-chunks of 32 cols
  const int mbase = group * 32;
  const int n0    = chunk * 32;
  const int wave  = tid >> 6;
  const int lane  = tid & 63;
  const int l15   = lane & 15;
  const int q8    = (lane >> 4) * 8;
  const int kb    = wave * 512;     // K split 4 ways across waves

  // per-group flag arrays: 64 chunks x 64B slots (16 u32 stride), monotone gens
  unsigned* sgen = (unsigned*)(ws + group * 8192);          // S-chunk ready: value t+1
  unsigned* hgen = (unsigned*)(ws + group * 8192 + 4096);   // h-chunk ready: value t+1
  float* Sf0 = (float*)(ws + 32768);                 // fp32 state master, ping
  float* Sf1 = (float*)(ws + 32768 + 1015808);       // pong
  short* Sb0 = (short*)(ws + 32768 + 2031616);       // bf16 state, ping
  short* Sb1 = (short*)(ws + 32768 + 2539520);       // pong
  short* hb  = (short*)(ws + 32768 + 3047424);       // bf16 h buffer [128][2048]

  __shared__ float red[4][16][65];  // +1 pad: conflict-free cross-wave reduce

  // ---- one-time: load & convert weight B-fragments into registers ----
  // B-frag layout (verified m89): n = lane&15 (row of W), k = (lane>>4)*8+j contiguous
  short8 B1[16][2], B2[16][2];
#pragma unroll
  for (int ks = 0; ks < 16; ++ks) {
#pragma unroll
    for (int nt = 0; nt < 2; ++nt) {
      const float* p1 = W1 + (size_t)(n0 + nt * 16 + l15) * WID + (kb + ks * 32 + q8);
      B1[ks][nt] = pack8(*(const f32x4*)p1, *(const f32x4*)(p1 + 4));
      const float* p2 = W2 + (size_t)(n0 + nt * 16 + l15) * WID + (kb + ks * 32 + q8);
      B2[ks][nt] = pack8(*(const f32x4*)p2, *(const f32x4*)(p2 + 4));
    }
  }

  const int m0 = mbase + l15;        // A-frag rows (m-tile 0)
  const int m1 = mbase + 16 + l15;   // m-tile 1

  const int o    = tid * 4;          // epilogue: 4 outputs per thread of 32x32 tile
  const int ml   = o >> 5;
  const int nl   = o & 31;
  const int mrow = mbase + ml;
  const int c0   = n0 + nl;          // this thread's absolute output column

  // biases for this thread's 4 output columns, loaded once (constant over t)
  const f32x4 b1r = *(const f32x4*)(b1f + n0 + nl);
  const f32x4 b2r = *(const f32x4*)(b2f + n0 + nl);

  short8 xa[8], xb[8];   // double-buffered in-flight operand blocks

#pragma unroll 1
  for (int t = 0; t < NSTEPS; ++t) {
    const float* SfOld = (t & 1) ? Sf1 : Sf0;
    float*       SfNew = (t & 1) ? Sf0 : Sf1;
    const short* SbOld = (t & 1) ? Sb1 : Sb0;
    short*       SbNew = (t & 1) ? Sb0 : Sb1;

    // ================= phase 1: u = s_in @ W1^T ; h = |u + b1| =================
    f32x4 a00{}, a01{}, a10{}, a11{};
    f32x4 prevv;
    if (t == 0) {
      // state is zero: only the x_t part contributes (wave 0, ks 0..1)
      prevv = (c0 < 64) ? *(const f32x4*)(inp + (size_t)mrow * 64 + c0)
                        : f32x4{0.f, 0.f, 0.f, 0.f};
      if (kb == 0) {
        const float* q0_ = inp + (size_t)m0 * 64 + q8;
        const float* q1_ = inp + (size_t)m1 * 64 + q8;
        short8 x0 = pack8(*(const f32x4*)q0_, *(const f32x4*)(q0_ + 4));
        short8 x1 = pack8(*(const f32x4*)q1_, *(const f32x4*)(q1_ + 4));
        short8 x2 = pack8(*(const f32x4*)(q0_ + 32), *(const f32x4*)(q0_ + 36));
        short8 x3 = pack8(*(const f32x4*)(q1_ + 32), *(const f32x4*)(q1_ + 36));
        a00 = __builtin_amdgcn_mfma_f32_16x16x32_bf16(x0, B1[0][0], a00, 0, 0, 0);
        a01 = __builtin_amdgcn_mfma_f32_16x16x32_bf16(x0, B1[0][1], a01, 0, 0, 0);
        a10 = __builtin_amdgcn_mfma_f32_16x16x32_bf16(x1, B1[0][0], a10, 0, 0, 0);
        a11 = __builtin_amdgcn_mfma_f32_16x16x32_bf16(x1, B1[0][1], a11, 0, 0, 0);
        a00 = __builtin_amdgcn_mfma_f32_16x16x32_bf16(x2, B1[1][0], a00, 0, 0, 0);
        a01 = __builtin_amdgcn_mfma_f32_16x16x32_bf16(x2, B1[1][1], a01, 0, 0, 0);
        a10 = __builtin_amdgcn_mfma_f32_16x16x32_bf16(x3, B1[1][0], a10, 0, 0, 0);
        a11 = __builtin_amdgcn_mfma_f32_16x16x32_bf16(x3, B1[1][1], a11, 0, 0, 0);
      }
    } else {
      // 4-block pipelined: wait(b)/load(b) overlap MFMA(b-1)
      P1WAIT(0);
      // hoisted epilogue prev (producer chunk-2 covered by P1WAIT(0) lane 16)
      if (c0 < 64) prevv = *(const f32x4*)(inp + ((size_t)t * NB + mrow) * 64 + c0);
      else         prevv = ald_f4(SfOld + (size_t)mrow * SS + (c0 - 64));
      P1LOAD(0, xa);
      P1WAIT(1); P1LOAD(1, xb); P1MFMA(0, xa);
      P1WAIT(2); P1LOAD(2, xa); P1MFMA(1, xb);
      P1WAIT(3); P1LOAD(3, xb); P1MFMA(2, xa);
      P1MFMA(3, xb);
    }
#pragma unroll
    for (int r = 0; r < 4; ++r) {            // ridx = mt*8 + nt*4 + r
      red[wave][r][lane]      = a00[r];
      red[wave][4 + r][lane]  = a01[r];
      red[wave][8 + r][lane]  = a10[r];
      red[wave][12 + r][lane] = a11[r];
    }
    __syncthreads();
    {
      short4v hv;
#pragma unroll
      for (int j = 0; j < 4; ++j) {
        const int nn   = nl + j;
        const int lidx = ((ml >> 2) & 3) * 16 + (nn & 15);   // C layout: lane=(row>>2)*16+col
        const int ridx = (ml >> 4) * 8 + (nn >> 4) * 4 + (ml & 3);
        float s = red[0][ridx][lidx] + red[1][ridx][lidx]
                + red[2][ridx][lidx] + red[3][ridx][lidx];
        s += b1r[j];
        hv[j] = f2bf(fabsf(s));
      }
      union { short4v s; u64 u; } hu; hu.s = hv;
      ast64(hb + (size_t)mrow * WID + (n0 + nl), hu.u);
    }
    __syncthreads();   // all 4 waves' h stores drained (vmcnt0) before signal
    if (tid == 0)
      __hip_atomic_store(hgen + chunk * 16, (unsigned)t + 1,
                         __ATOMIC_RELAXED, __HIP_MEMORY_SCOPE_AGENT);

    // ================= phase 2: g = h @ W2^T ; state update =================
    f32x4 c00{}, c01{}, c10{}, c11{};
    {
      const short* h0 = hb + (size_t)m0 * WID + (kb + q8);
      const short* h1 = hb + (size_t)m1 * WID + (kb + q8);
      P2WAIT(0); P2LOAD(0, xa);
      P2WAIT(1); P2LOAD(1, xb); P2MFMA(0, xa);
      P2WAIT(2); P2LOAD(2, xa); P2MFMA(1, xb);
      P2WAIT(3); P2LOAD(3, xb); P2MFMA(2, xa);
      P2MFMA(3, xb);
    }
#pragma unroll
    for (int r = 0; r < 4; ++r) {
      red[wave][r][lane]      = c00[r];
      red[wave][4 + r][lane]  = c01[r];
      red[wave][8 + r][lane]  = c10[r];
      red[wave][12 + r][lane] = c11[r];
    }
    __syncthreads();
    if (t < NSTEPS - 1) {
      if (n0 < SS) {   // cols >= SS are dropped by the shift (except final step)
        f32x4 gv;
#pragma unroll
        for (int j = 0; j < 4; ++j) {
          const int nn   = nl + j;
          const int lidx = ((ml >> 2) & 3) * 16 + (nn & 15);
          const int ridx = (ml >> 4) * 8 + (nn >> 4) * 4 + (ml & 3);
          gv[j] = red[0][ridx][lidx] + red[1][ridx][lidx]
                + red[2][ridx][lidx] + red[3][ridx][lidx] + b2r[j];
        }
        f32x4 sv; short4v sb;
#pragma unroll
        for (int j = 0; j < 4; ++j) {
          float vv = 0.9f * prevv[j] + 0.1f * gv[j];
          sv[j] = vv; sb[j] = f2bf(vv);
        }
        union { f32x4 f; u64 u[2]; } sfu; sfu.f = sv;
        float* pf = SfNew + (size_t)mrow * SS + c0;
        ast64(pf, sfu.u[0]);
        ast64(pf + 2, sfu.u[1]);
        union { short4v s; u64 u; } sbu; sbu.s = sb;
        ast64(SbNew + (size_t)mrow * SS + c0, sbu.u);
      }
      __syncthreads();   // all 4 waves' S stores drained before signal
      if (tid == 0 && chunk < 62)
        __hip_atomic_store(sgen + chunk * 16, (unsigned)t + 1,
                           __ATOMIC_RELAXED, __HIP_MEMORY_SCOPE_AGENT);
    } else {
      // final step: out[m, :] = 0.9*s_in[m, 1984+o] + 0.1*(g+b2)[m, 1984+o]
      if (n0 >= SS) {
        f32x4 gv;
#pragma unroll
        for (int j = 0; j < 4; ++j) {
          const int nn   = nl + j;
          const int lidx = ((ml >> 2) & 3) * 16 + (nn & 15);
          const int ridx = (ml >> 4) * 8 + (nn >> 4) * 4 + (ml & 3);
          gv[j] = red[0][ridx][lidx] + red[1][ridx][lidx]
                + red[2][ridx][lidx] + red[3][ridx][lidx] + b2r[j];
        }
        f32x4 ov;
#pragma unroll
        for (int j = 0; j < 4; ++j) ov[j] = 0.9f * prevv[j] + 0.1f * gv[j];
        *(f32x4*)(out + (size_t)mrow * 64 + (c0 - SS)) = ov;
      }
    }
  }
}

extern "C" void kernel_launch(void* const* d_in, const int* in_sizes, int n_in,
                              void* d_out, int out_size, void* d_ws, size_t ws_size,
                              hipStream_t stream)
{
  (void)in_sizes; (void)n_in; (void)out_size; (void)ws_size;
  const float* inp = (const float*)d_in[0];
  const float* W1  = (const float*)d_in[1];
  const float* b1  = (const float*)d_in[2];
  const float* W2  = (const float*)d_in[3];
  const float* b2  = (const float*)d_in[4];
  float* out = (float*)d_out;

  // zero the flag area (ws is re-poisoned to 0xAA before every timed launch)
  hipMemsetAsync(d_ws, 0, 32768, stream);
  resrnn_kernel<<<dim3(256), dim3(256), 0, stream>>>(
      inp, W1, b1, W2, b2, out, (unsigned char*)d_ws);
}

// Round 8
// 1632.250 us; speedup vs baseline: 2.3002x; 1.4561x over previous
//
#include <hip/hip_runtime.h>
#include <stdint.h>

// ResRnn: T=128 sequential steps of  h=|s@W1^T+b1|; s'=0.9*shift(s)+0.1*(h@W2^T+b2)
// Persistent kernel: 256 WGs (1/CU), 4 independent batch-groups of 64 WGs,
// bf16 weights resident in VGPRs as MFMA B-frags.
// R6 protocol (proven 2425us): per-chunk monotone gen flags, 64B-strided slots,
//     tid0 store AFTER __syncthreads; relaxed agent-scope (sc1) data stores.
// R7 REVERTED (packed flags + atomic counters: RMW contention). R8 REVERTED
//     (acquire-fence + cached loads: L2 invalidate thrash). R9 neutral-kept
//     (prevv hoist + sticky poll). R11 ~neutral-kept (4-block pipeline).
//     R12 REVERTED (u-space rewrite: math wrong — concat is a shift).
// R13 neutral-kept (busy-spin) — BUT diagnostic: VALUBusy unchanged (3.67%)
//     with s_sleep removed => waves are NOT poll-spinning; they stall in
//     s_waitcnt vmcnt on operand loads. Exchange DATA PATH is the sink.
// R14 (this round): operand loads move off the TCC ATOMIC pipe.
//     ald_s8 (2x 8B agent atomic loads) -> ONE plain global_load_dwordx4 with
//     sc1 (inline asm). sc1 is what gives agent-coherent (MALL-direct) reads;
//     atomicity contributed nothing but forced per-lane atomic-op processing:
//     4.2M 8B atomic ops/phase chip-wide ~ the measured 9.3us/phase. Plain
//     sc1 loads coalesce to 128B lines (~262K line-reqs/phase).
//     Pipeline: per phase ONE sticky flag wait (hoisted before all issues so
//     the poll's compiler vmcnt(0) can't drain the pipeline), then 4 blocks of
//     8 asm loads with counted vmcnt(8) + sched_barrier(0) fences (rule #18)
//     so block b+1's loads fly under block b's MFMAs.
// Buffer safety unchanged: S ping-pong + single h buffer.

#define NSTEPS 128
#define NB 128
#define WID 2048
#define SS 1984   // recurrent state width (WIDTH - INPUT_SIZE)

typedef __attribute__((ext_vector_type(8))) short short8;
typedef __attribute__((ext_vector_type(4))) short short4v;
typedef __attribute__((ext_vector_type(4))) float f32x4;
typedef unsigned long long u64;

static __device__ __forceinline__ short f2bf(float f) {
  union { float f; unsigned u; } v; v.f = f;
  unsigned r = (v.u + 0x7fffu + ((v.u >> 16) & 1u)) >> 16;  // RNE
  return (short)r;
}

static __device__ __forceinline__ short8 pack8(f32x4 lo, f32x4 hi) {
  short8 r;
  r[0] = f2bf(lo[0]); r[1] = f2bf(lo[1]); r[2] = f2bf(lo[2]); r[3] = f2bf(lo[3]);
  r[4] = f2bf(hi[0]); r[5] = f2bf(hi[1]); r[6] = f2bf(hi[2]); r[7] = f2bf(hi[3]);
  return r;
}

// write-through store to the agent coherence point (LLC); does not dirty L2
static __device__ __forceinline__ void ast64(void* p, u64 v) {
  __hip_atomic_store((u64*)p, v, __ATOMIC_RELAXED, __HIP_MEMORY_SCOPE_AGENT);
}
// LLC-direct coherent flag load (atomic path OK: tiny volume)
static __device__ __forceinline__ unsigned ald32(const unsigned* p) {
  return __hip_atomic_load(p, __ATOMIC_RELAXED, __HIP_MEMORY_SCOPE_AGENT);
}

// R14: plain 16B agent-coherent load (sc1 = bypass stale L1/L2, read MALL).
// NO waitcnt inside — caller MUST fence with VMW() before consuming.
#define LLCLD(d, a) \
  asm volatile("global_load_dwordx4 %0, %1, off sc1" : "=&v"(d) : "v"(a))
// counted vmem wait + scheduler fence (rule #18: stop MFMA hoisting above it)
#define VMW(n) do { \
    asm volatile("s_waitcnt vmcnt(" #n ")" ::: "memory"); \
    __builtin_amdgcn_sched_barrier(0); \
  } while (0)

// ---- phase-1 issue macros (literal b: static reg indexing, rule #20) ----
#define P1ISSUE(b, X) do {                                                    \
    if (kb == 0 && (b) == 0) {  /* ks 0,1 = x_t input; ks 2,3 = Sb cols 0,32 */ \
      const float* q0_ = inp + ((size_t)t * NB + m0) * 64 + q8;               \
      const float* q1_ = inp + ((size_t)t * NB + m1) * 64 + q8;               \
      X[0] = pack8(*(const f32x4*)q0_, *(const f32x4*)(q0_ + 4));             \
      X[1] = pack8(*(const f32x4*)q1_, *(const f32x4*)(q1_ + 4));             \
      X[2] = pack8(*(const f32x4*)(q0_ + 32), *(const f32x4*)(q0_ + 36));     \
      X[3] = pack8(*(const f32x4*)(q1_ + 32), *(const f32x4*)(q1_ + 36));     \
      LLCLD(X[4], (SbOld + (size_t)m0 * SS + q8));                            \
      LLCLD(X[5], (SbOld + (size_t)m1 * SS + q8));                            \
      LLCLD(X[6], (SbOld + (size_t)m0 * SS + 32 + q8));                       \
      LLCLD(X[7], (SbOld + (size_t)m1 * SS + 32 + q8));                       \
    } else {                                                                  \
      const short* s0_ = SbOld + (size_t)m0 * SS + (kb + 4 * (b) * 32 - 64 + q8); \
      const short* s1_ = SbOld + (size_t)m1 * SS + (kb + 4 * (b) * 32 - 64 + q8); \
      LLCLD(X[0], (s0_));      LLCLD(X[1], (s1_));                            \
      LLCLD(X[2], (s0_ + 32)); LLCLD(X[3], (s1_ + 32));                       \
      LLCLD(X[4], (s0_ + 64)); LLCLD(X[5], (s1_ + 64));                       \
      LLCLD(X[6], (s0_ + 96)); LLCLD(X[7], (s1_ + 96));                       \
    }                                                                         \
  } while (0)

#define P1MFMA(b, X) do {                                                     \
    a00 = __builtin_amdgcn_mfma_f32_16x16x32_bf16(X[0], B1[4*(b)+0][0], a00, 0,0,0); \
    a01 = __builtin_amdgcn_mfma_f32_16x16x32_bf16(X[0], B1[4*(b)+0][1], a01, 0,0,0); \
    a10 = __builtin_amdgcn_mfma_f32_16x16x32_bf16(X[1], B1[4*(b)+0][0], a10, 0,0,0); \
    a11 = __builtin_amdgcn_mfma_f32_16x16x32_bf16(X[1], B1[4*(b)+0][1], a11, 0,0,0); \
    a00 = __builtin_amdgcn_mfma_f32_16x16x32_bf16(X[2], B1[4*(b)+1][0], a00, 0,0,0); \
    a01 = __builtin_amdgcn_mfma_f32_16x16x32_bf16(X[2], B1[4*(b)+1][1], a01, 0,0,0); \
    a10 = __builtin_amdgcn_mfma_f32_16x16x32_bf16(X[3], B1[4*(b)+1][0], a10, 0,0,0); \
    a11 = __builtin_amdgcn_mfma_f32_16x16x32_bf16(X[3], B1[4*(b)+1][1], a11, 0,0,0); \
    a00 = __builtin_amdgcn_mfma_f32_16x16x32_bf16(X[4], B1[4*(b)+2][0], a00, 0,0,0); \
    a01 = __builtin_amdgcn_mfma_f32_16x16x32_bf16(X[4], B1[4*(b)+2][1], a01, 0,0,0); \
    a10 = __builtin_amdgcn_mfma_f32_16x16x32_bf16(X[5], B1[4*(b)+2][0], a10, 0,0,0); \
    a11 = __builtin_amdgcn_mfma_f32_16x16x32_bf16(X[5], B1[4*(b)+2][1], a11, 0,0,0); \
    a00 = __builtin_amdgcn_mfma_f32_16x16x32_bf16(X[6], B1[4*(b)+3][0], a00, 0,0,0); \
    a01 = __builtin_amdgcn_mfma_f32_16x16x32_bf16(X[6], B1[4*(b)+3][1], a01, 0,0,0); \
    a10 = __builtin_amdgcn_mfma_f32_16x16x32_bf16(X[7], B1[4*(b)+3][0], a10, 0,0,0); \
    a11 = __builtin_amdgcn_mfma_f32_16x16x32_bf16(X[7], B1[4*(b)+3][1], a11, 0,0,0); \
  } while (0)

#define P2ISSUE(b, X) do {                                                    \
    LLCLD(X[0], (h0 + (4*(b)+0) * 32)); LLCLD(X[1], (h1 + (4*(b)+0) * 32));   \
    LLCLD(X[2], (h0 + (4*(b)+1) * 32)); LLCLD(X[3], (h1 + (4*(b)+1) * 32));   \
    LLCLD(X[4], (h0 + (4*(b)+2) * 32)); LLCLD(X[5], (h1 + (4*(b)+2) * 32));   \
    LLCLD(X[6], (h0 + (4*(b)+3) * 32)); LLCLD(X[7], (h1 + (4*(b)+3) * 32));   \
  } while (0)

#define P2MFMA(b, X) do {                                                     \
    c00 = __builtin_amdgcn_mfma_f32_16x16x32_bf16(X[0], B2[4*(b)+0][0], c00, 0,0,0); \
    c01 = __builtin_amdgcn_mfma_f32_16x16x32_bf16(X[0], B2[4*(b)+0][1], c01, 0,0,0); \
    c10 = __builtin_amdgcn_mfma_f32_16x16x32_bf16(X[1], B2[4*(b)+0][0], c10, 0,0,0); \
    c11 = __builtin_amdgcn_mfma_f32_16x16x32_bf16(X[1], B2[4*(b)+0][1], c11, 0,0,0); \
    c00 = __builtin_amdgcn_mfma_f32_16x16x32_bf16(X[2], B2[4*(b)+1][0], c00, 0,0,0); \
    c01 = __builtin_amdgcn_mfma_f32_16x16x32_bf16(X[2], B2[4*(b)+1][1], c01, 0,0,0); \
    c10 = __builtin_amdgcn_mfma_f32_16x16x32_bf16(X[3], B2[4*(b)+1][0], c10, 0,0,0); \
    c11 = __builtin_amdgcn_mfma_f32_16x16x32_bf16(X[3], B2[4*(b)+1][1], c11, 0,0,0); \
    c00 = __builtin_amdgcn_mfma_f32_16x16x32_bf16(X[4], B2[4*(b)+2][0], c00, 0,0,0); \
    c01 = __builtin_amdgcn_mfma_f32_16x16x32_bf16(X[4], B2[4*(b)+2][1], c01, 0,0,0); \
    c10 = __builtin_amdgcn_mfma_f32_16x16x32_bf16(X[5], B2[4*(b)+2][0], c10, 0,0,0); \
    c11 = __builtin_amdgcn_mfma_f32_16x16x32_bf16(X[5], B2[4*(b)+2][1], c11, 0,0,0); \
    c00 = __builtin_amdgcn_mfma_f32_16x16x32_bf16(X[6], B2[4*(b)+3][0], c00, 0,0,0); \
    c01 = __builtin_amdgcn_mfma_f32_16x16x32_bf16(X[6], B2[4*(b)+3][1], c01, 0,0,0); \
    c10 = __builtin_amdgcn_mfma_f32_16x16x32_bf16(X[7], B2[4*(b)+3][0], c10, 0,0,0); \
    c11 = __builtin_amdgcn_mfma_f32_16x16x32_bf16(X[7], B2[4*(b)+3][1], c11, 0,0,0); \
  } while (0)

__global__ __launch_bounds__(256, 1)
void resrnn_kernel(const float* __restrict__ inp, const float* __restrict__ W1,
                   const float* __restrict__ b1f, const float* __restrict__ W2,
                   const float* __restrict__ b2f, float* __restrict__ out,
                   unsigned char* __restrict__ ws)
{
  const int tid   = threadIdx.x;
  const int bid   = blockIdx.x;
  const int group = bid & 3;        // 4 independent batch groups (32 rows each)
  const int chunk = bid >> 2;       // 64 N-chunks of 32 cols
  const int mbase = group * 32;
  const int n0    = chunk * 32;
  const int wave  = tid >> 6;
  const int lane  = tid & 63;
  const int l15   = lane & 15;
  const int q8    = (lane >> 4) * 8;
  const int kb    = wave * 512;     // K split 4 ways across waves

  // per-group flag arrays: 64 chunks x 64B slots (16 u32 stride), monotone gens
  unsigned* sgen = (unsigned*)(ws + group * 8192);          // S-chunk ready: value t+1
  unsigned* hgen = (unsigned*)(ws + group * 8192 + 4096);   // h-chunk ready: value t+1
  float* Sf0 = (float*)(ws + 32768);                 // fp32 state master, ping
  float* Sf1 = (float*)(ws + 32768 + 1015808);       // pong
  short* Sb0 = (short*)(ws + 32768 + 2031616);       // bf16 state, ping
  short* Sb1 = (short*)(ws + 32768 + 2539520);       // pong
  short* hb  = (short*)(ws + 32768 + 3047424);       // bf16 h buffer [128][2048]

  __shared__ float red[4][16][65];  // +1 pad: conflict-free cross-wave reduce

  // ---- one-time: load & convert weight B-fragments into registers ----
  // B-frag layout (verified m89): n = lane&15 (row of W), k = (lane>>4)*8+j contiguous
  short8 B1[16][2], B2[16][2];
#pragma unroll
  for (int ks = 0; ks < 16; ++ks) {
#pragma unroll
    for (int nt = 0; nt < 2; ++nt) {
      const float* p1 = W1 + (size_t)(n0 + nt * 16 + l15) * WID + (kb + ks * 32 + q8);
      B1[ks][nt] = pack8(*(const f32x4*)p1, *(const f32x4*)(p1 + 4));
      const float* p2 = W2 + (size_t)(n0 + nt * 16 + l15) * WID + (kb + ks * 32 + q8);
      B2[ks][nt] = pack8(*(const f32x4*)p2, *(const f32x4*)(p2 + 4));
    }
  }

  const int m0 = mbase + l15;        // A-frag rows (m-tile 0)
  const int m1 = mbase + 16 + l15;   // m-tile 1

  const int o    = tid * 4;          // epilogue: 4 outputs per thread of 32x32 tile
  const int ml   = o >> 5;
  const int nl   = o & 31;
  const int mrow = mbase + ml;
  const int c0   = n0 + nl;          // this thread's absolute output column

  // biases for this thread's 4 output columns, loaded once (constant over t)
  const f32x4 b1r = *(const f32x4*)(b1f + n0 + nl);
  const f32x4 b2r = *(const f32x4*)(b2f + n0 + nl);

  // phase-1 wait setup (R9): lanes 0..15 poll the 16 A-operand producers;
  // lane 16 polls chunk-2 (covers the hoisted fp32 prev read).
  const int p1pc = 16 * wave + l15 - 2;
  const bool p1needA = (lane < 16) && (p1pc >= 0);
  const bool p1needB = (lane == 16) && (chunk >= 2);
  const unsigned* p1fp =
      p1needA ? (sgen + p1pc * 16)
              : (sgen + (chunk >= 2 ? chunk - 2 : 0) * 16);
  // phase-2 wait setup: lanes 0..15 poll h-chunks 16w+l15
  const unsigned* p2fp = hgen + (16 * wave + l15) * 16;

  short8 xa[8], xb[8];   // double-buffered in-flight operand blocks

#pragma unroll 1
  for (int t = 0; t < NSTEPS; ++t) {
    const float* SfOld = (t & 1) ? Sf1 : Sf0;
    float*       SfNew = (t & 1) ? Sf0 : Sf1;
    const short* SbOld = (t & 1) ? Sb1 : Sb0;
    short*       SbNew = (t & 1) ? Sb0 : Sb1;

    // ================= phase 1: u = s_in @ W1^T ; h = |u + b1| =================
    f32x4 a00{}, a01{}, a10{}, a11{};
    f32x4 prevv;
    if (t == 0) {
      // state is zero: only the x_t part contributes (wave 0, ks 0..1)
      prevv = (c0 < 64) ? *(const f32x4*)(inp + (size_t)mrow * 64 + c0)
                        : f32x4{0.f, 0.f, 0.f, 0.f};
      if (kb == 0) {
        const float* q0_ = inp + (size_t)m0 * 64 + q8;
        const float* q1_ = inp + (size_t)m1 * 64 + q8;
        short8 x0 = pack8(*(const f32x4*)q0_, *(const f32x4*)(q0_ + 4));
        short8 x1 = pack8(*(const f32x4*)q1_, *(const f32x4*)(q1_ + 4));
        short8 x2 = pack8(*(const f32x4*)(q0_ + 32), *(const f32x4*)(q0_ + 36));
        short8 x3 = pack8(*(const f32x4*)(q1_ + 32), *(const f32x4*)(q1_ + 36));
        a00 = __builtin_amdgcn_mfma_f32_16x16x32_bf16(x0, B1[0][0], a00, 0, 0, 0);
        a01 = __builtin_amdgcn_mfma_f32_16x16x32_bf16(x0, B1[0][1], a01, 0, 0, 0);
        a10 = __builtin_amdgcn_mfma_f32_16x16x32_bf16(x1, B1[0][0], a10, 0, 0, 0);
        a11 = __builtin_amdgcn_mfma_f32_16x16x32_bf16(x1, B1[0][1], a11, 0, 0, 0);
        a00 = __builtin_amdgcn_mfma_f32_16x16x32_bf16(x2, B1[1][0], a00, 0, 0, 0);
        a01 = __builtin_amdgcn_mfma_f32_16x16x32_bf16(x2, B1[1][1], a01, 0, 0, 0);
        a10 = __builtin_amdgcn_mfma_f32_16x16x32_bf16(x3, B1[1][0], a10, 0, 0, 0);
        a11 = __builtin_amdgcn_mfma_f32_16x16x32_bf16(x3, B1[1][1], a11, 0, 0, 0);
      }
    } else {
      // ONE sticky wait for all of this wave's producers (before any issue,
      // so the poll's compiler vmcnt(0) can't drain the load pipeline)
      {
        const unsigned tgt = (unsigned)t;
        bool pend = p1needA || p1needB;
        for (;;) {
          if (pend && ald32(p1fp) >= tgt) pend = false;
          if (__ballot(pend) == 0ull) break;
        }
      }
      // hoisted epilogue prev (producer chunk-2 covered by lane-16 wait)
      if (c0 < 64) {
        prevv = *(const f32x4*)(inp + ((size_t)t * NB + mrow) * 64 + c0);
      } else {
        LLCLD(prevv, (SfOld + (size_t)mrow * SS + (c0 - 64)));
      }
      // counted-vmcnt pipeline: block b+1's loads fly under block b's MFMAs
      P1ISSUE(0, xa); P1ISSUE(1, xb);
      VMW(8);  P1MFMA(0, xa);
      P1ISSUE(2, xa);
      VMW(8);  P1MFMA(1, xb);
      P1ISSUE(3, xb);
      VMW(8);  P1MFMA(2, xa);
      VMW(0);  P1MFMA(3, xb);
    }
#pragma unroll
    for (int r = 0; r < 4; ++r) {            // ridx = mt*8 + nt*4 + r
      red[wave][r][lane]      = a00[r];
      red[wave][4 + r][lane]  = a01[r];
      red[wave][8 + r][lane]  = a10[r];
      red[wave][12 + r][lane] = a11[r];
    }
    __syncthreads();
    {
      short4v hv;
#pragma unroll
      for (int j = 0; j < 4; ++j) {
        const int nn   = nl + j;
        const int lidx = ((ml >> 2) & 3) * 16 + (nn & 15);   // C layout: lane=(row>>2)*16+col
        const int ridx = (ml >> 4) * 8 + (nn >> 4) * 4 + (ml & 3);
        float s = red[0][ridx][lidx] + red[1][ridx][lidx]
                + red[2][ridx][lidx] + red[3][ridx][lidx];
        s += b1r[j];
        hv[j] = f2bf(fabsf(s));
      }
      union { short4v s; u64 u; } hu; hu.s = hv;
      ast64(hb + (size_t)mrow * WID + (n0 + nl), hu.u);
    }
    __syncthreads();   // all 4 waves' h stores drained (vmcnt0) before signal
    if (tid == 0)
      __hip_atomic_store(hgen + chunk * 16, (unsigned)t + 1,
                         __ATOMIC_RELAXED, __HIP_MEMORY_SCOPE_AGENT);

    // ================= phase 2: g = h @ W2^T ; state update =================
    f32x4 c00{}, c01{}, c10{}, c11{};
    {
      const short* h0 = hb + (size_t)m0 * WID + (kb + q8);
      const short* h1 = hb + (size_t)m1 * WID + (kb + q8);
      {  // one sticky wait for this wave's 16 h-producers
        const unsigned tgt = (unsigned)t + 1;
        bool pend = (lane < 16);
        for (;;) {
          if (pend && ald32(p2fp) >= tgt) pend = false;
          if (__ballot(pend) == 0ull) break;
        }
      }
      P2ISSUE(0, xa); P2ISSUE(1, xb);
      VMW(8);  P2MFMA(0, xa);
      P2ISSUE(2, xa);
      VMW(8);  P2MFMA(1, xb);
      P2ISSUE(3, xb);
      VMW(8);  P2MFMA(2, xa);
      VMW(0);  P2MFMA(3, xb);
    }
#pragma unroll
    for (int r = 0; r < 4; ++r) {
      red[wave][r][lane]      = c00[r];
      red[wave][4 + r][lane]  = c01[r];
      red[wave][8 + r][lane]  = c10[r];
      red[wave][12 + r][lane] = c11[r];
    }
    __syncthreads();
    if (t < NSTEPS - 1) {
      if (n0 < SS) {   // cols >= SS are dropped by the shift (except final step)
        f32x4 gv;
#pragma unroll
        for (int j = 0; j < 4; ++j) {
          const int nn   = nl + j;
          const int lidx = ((ml >> 2) & 3) * 16 + (nn & 15);
          const int ridx = (ml >> 4) * 8 + (nn >> 4) * 4 + (ml & 3);
          gv[j] = red[0][ridx][lidx] + red[1][ridx][lidx]
                + red[2][ridx][lidx] + red[3][ridx][lidx] + b2r[j];
        }
        f32x4 sv; short4v sb;
#pragma unroll
        for (int j = 0; j < 4; ++j) {
          float vv = 0.9f * prevv[j] + 0.1f * gv[j];
          sv[j] = vv; sb[j] = f2bf(vv);
        }
        union { f32x4 f; u64 u[2]; } sfu; sfu.f = sv;
        float* pf = SfNew + (size_t)mrow * SS + c0;
        ast64(pf, sfu.u[0]);
        ast64(pf + 2, sfu.u[1]);
        union { short4v s; u64 u; } sbu; sbu.s = sb;
        ast64(SbNew + (size_t)mrow * SS + c0, sbu.u);
      }
      __syncthreads();   // all 4 waves' S stores drained before signal
      if (tid == 0 && chunk < 62)
        __hip_atomic_store(sgen + chunk * 16, (unsigned)t + 1,
                           __ATOMIC_RELAXED, __HIP_MEMORY_SCOPE_AGENT);
    } else {
      // final step: out[m, :] = 0.9*s_in[m, 1984+o] + 0.1*(g+b2)[m, 1984+o]
      if (n0 >= SS) {
        f32x4 gv;
#pragma unroll
        for (int j = 0; j < 4; ++j) {
          const int nn   = nl + j;
          const int lidx = ((ml >> 2) & 3) * 16 + (nn & 15);
          const int ridx = (ml >> 4) * 8 + (nn >> 4) * 4 + (ml & 3);
          gv[j] = red[0][ridx][lidx] + red[1][ridx][lidx]
                + red[2][ridx][lidx] + red[3][ridx][lidx] + b2r[j];
        }
        f32x4 ov;
#pragma unroll
        for (int j = 0; j < 4; ++j) ov[j] = 0.9f * prevv[j] + 0.1f * gv[j];
        *(f32x4*)(out + (size_t)mrow * 64 + (c0 - SS)) = ov;
      }
    }
  }
}

extern "C" void kernel_launch(void* const* d_in, const int* in_sizes, int n_in,
                              void* d_out, int out_size, void* d_ws, size_t ws_size,
                              hipStream_t stream)
{
  (void)in_sizes; (void)n_in; (void)out_size; (void)ws_size;
  const float* inp = (const float*)d_in[0];
  const float* W1  = (const float*)d_in[1];
  const float* b1  = (const float*)d_in[2];
  const float* W2  = (const float*)d_in[3];
  const float* b2  = (const float*)d_in[4];
  float* out = (float*)d_out;

  // zero the flag area (ws is re-poisoned to 0xAA before every timed launch)
  hipMemsetAsync(d_ws, 0, 32768, stream);
  resrnn_kernel<<<dim3(256), dim3(256), 0, stream>>>(
      inp, W1, b1, W2, b2, out, (unsigned char*)d_ws);
}

// Round 9
// 1068.410 us; speedup vs baseline: 3.5141x; 1.5277x over previous
//
#include <hip/hip_runtime.h>
#include <stdint.h>

// ResRnn: T=128 sequential steps of  h=|s@W1^T+b1|; s'=0.9*shift(s)+0.1*(h@W2^T+b2)
// Persistent kernel: 256 WGs (1/CU), 4 independent batch-groups of 64 WGs,
// bf16 weights resident in VGPRs as MFMA B-frags.
// R6 protocol (proven): per-chunk monotone gen flags, 64B-strided slots,
//     tid0 store AFTER __syncthreads; relaxed agent-scope data stores.
// R14 (1632us, -31%): operand loads = plain global_load_dwordx4 sc1 (inline
//     asm) + counted vmcnt(8) pipeline + sched_barrier fences; one hoisted
//     sticky flag-wait per phase. MfmaUtil 4.7->6.9, VALUBusy 3.7->6.2.
// R15 (this round): K-TILED SLAB LAYOUTS for all exchanged buffers.
//     Old row-major reads: one wave LLCLD = 16 rows x 64B = 16 half-used
//     128B lines + ~16 TA address-clocks. New layouts
//       SbT[248 kblk][128 row][8 bf16], hbT[256][128][8], SfT[248][128][8]f32
//     make each LLCLD read 4 slabs x 256B contiguous = 8 FULLY-USED lines,
//     4 TA segments. Epilogue thread-remap (ml=(tid&63)>>1, nl=wave*8+
//     (tid&1)*4 — bijection, free via the LDS reduce) makes h/Sb/Sf stores
//     contiguous per wave and prevv a single coalesced load at toff-8192.
//     Producer/consumer both address (slab=j/8, row, j&7): bit-identical
//     values, different storage order. Flags/waits/pipeline: verbatim R14.
// Buffer safety unchanged: S ping-pong + single h buffer (same sizes/offsets).

#define NSTEPS 128
#define NB 128
#define WID 2048
#define SS 1984   // recurrent state width (WIDTH - INPUT_SIZE)

typedef __attribute__((ext_vector_type(8))) short short8;
typedef __attribute__((ext_vector_type(4))) short short4v;
typedef __attribute__((ext_vector_type(4))) float f32x4;
typedef unsigned long long u64;

static __device__ __forceinline__ short f2bf(float f) {
  union { float f; unsigned u; } v; v.f = f;
  unsigned r = (v.u + 0x7fffu + ((v.u >> 16) & 1u)) >> 16;  // RNE
  return (short)r;
}

static __device__ __forceinline__ short8 pack8(f32x4 lo, f32x4 hi) {
  short8 r;
  r[0] = f2bf(lo[0]); r[1] = f2bf(lo[1]); r[2] = f2bf(lo[2]); r[3] = f2bf(lo[3]);
  r[4] = f2bf(hi[0]); r[5] = f2bf(hi[1]); r[6] = f2bf(hi[2]); r[7] = f2bf(hi[3]);
  return r;
}

// write-through store to the agent coherence point (LLC); does not dirty L2
static __device__ __forceinline__ void ast64(void* p, u64 v) {
  __hip_atomic_store((u64*)p, v, __ATOMIC_RELAXED, __HIP_MEMORY_SCOPE_AGENT);
}
// LLC-direct coherent flag load
static __device__ __forceinline__ unsigned ald32(const unsigned* p) {
  return __hip_atomic_load(p, __ATOMIC_RELAXED, __HIP_MEMORY_SCOPE_AGENT);
}

// plain 16B agent-coherent load (sc1 = bypass stale L1/L2, read MALL).
// NO waitcnt inside — caller MUST fence with VMW() before consuming.
#define LLCLD(d, a) \
  asm volatile("global_load_dwordx4 %0, %1, off sc1" : "=&v"(d) : "v"(a))
// counted vmem wait + scheduler fence (rule #18: stop MFMA hoisting above it)
#define VMW(n) do { \
    asm volatile("s_waitcnt vmcnt(" #n ")" ::: "memory"); \
    __builtin_amdgcn_sched_barrier(0); \
  } while (0)

// ---- phase-1 issue macros (literal b: static reg indexing, rule #20) ----
// Tiled state reads: block b, sub i: slab base = kb/8 + 16b + 4i - 8 (+slabL).
#define P1ISSUE(b, X) do {                                                    \
    if (kb == 0 && (b) == 0) {  /* ks 0,1 = x_t input; ks 2,3 = state slabs 0..7 */ \
      const float* q0_ = inp + ((size_t)t * NB + m0) * 64 + q8;               \
      const float* q1_ = inp + ((size_t)t * NB + m1) * 64 + q8;               \
      X[0] = pack8(*(const f32x4*)q0_, *(const f32x4*)(q0_ + 4));             \
      X[1] = pack8(*(const f32x4*)q1_, *(const f32x4*)(q1_ + 4));             \
      X[2] = pack8(*(const f32x4*)(q0_ + 32), *(const f32x4*)(q0_ + 36));     \
      X[3] = pack8(*(const f32x4*)(q1_ + 32), *(const f32x4*)(q1_ + 36));     \
      const short* s_ = SbOld + (size_t)slabL * 1024;                         \
      LLCLD(X[4], (s_ + rowoff0));           LLCLD(X[5], (s_ + rowoff1));     \
      LLCLD(X[6], (s_ + 4096 + rowoff0));    LLCLD(X[7], (s_ + 4096 + rowoff1)); \
    } else {                                                                  \
      const short* s_ = SbOld + (size_t)(kb / 8 + 16 * (b) - 8 + slabL) * 1024; \
      LLCLD(X[0], (s_ + rowoff0));           LLCLD(X[1], (s_ + rowoff1));     \
      LLCLD(X[2], (s_ + 4096 + rowoff0));    LLCLD(X[3], (s_ + 4096 + rowoff1)); \
      LLCLD(X[4], (s_ + 8192 + rowoff0));    LLCLD(X[5], (s_ + 8192 + rowoff1)); \
      LLCLD(X[6], (s_ + 12288 + rowoff0));   LLCLD(X[7], (s_ + 12288 + rowoff1)); \
    }                                                                         \
  } while (0)

#define P1MFMA(b, X) do {                                                     \
    a00 = __builtin_amdgcn_mfma_f32_16x16x32_bf16(X[0], B1[4*(b)+0][0], a00, 0,0,0); \
    a01 = __builtin_amdgcn_mfma_f32_16x16x32_bf16(X[0], B1[4*(b)+0][1], a01, 0,0,0); \
    a10 = __builtin_amdgcn_mfma_f32_16x16x32_bf16(X[1], B1[4*(b)+0][0], a10, 0,0,0); \
    a11 = __builtin_amdgcn_mfma_f32_16x16x32_bf16(X[1], B1[4*(b)+0][1], a11, 0,0,0); \
    a00 = __builtin_amdgcn_mfma_f32_16x16x32_bf16(X[2], B1[4*(b)+1][0], a00, 0,0,0); \
    a01 = __builtin_amdgcn_mfma_f32_16x16x32_bf16(X[2], B1[4*(b)+1][1], a01, 0,0,0); \
    a10 = __builtin_amdgcn_mfma_f32_16x16x32_bf16(X[3], B1[4*(b)+1][0], a10, 0,0,0); \
    a11 = __builtin_amdgcn_mfma_f32_16x16x32_bf16(X[3], B1[4*(b)+1][1], a11, 0,0,0); \
    a00 = __builtin_amdgcn_mfma_f32_16x16x32_bf16(X[4], B1[4*(b)+2][0], a00, 0,0,0); \
    a01 = __builtin_amdgcn_mfma_f32_16x16x32_bf16(X[4], B1[4*(b)+2][1], a01, 0,0,0); \
    a10 = __builtin_amdgcn_mfma_f32_16x16x32_bf16(X[5], B1[4*(b)+2][0], a10, 0,0,0); \
    a11 = __builtin_amdgcn_mfma_f32_16x16x32_bf16(X[5], B1[4*(b)+2][1], a11, 0,0,0); \
    a00 = __builtin_amdgcn_mfma_f32_16x16x32_bf16(X[6], B1[4*(b)+3][0], a00, 0,0,0); \
    a01 = __builtin_amdgcn_mfma_f32_16x16x32_bf16(X[6], B1[4*(b)+3][1], a01, 0,0,0); \
    a10 = __builtin_amdgcn_mfma_f32_16x16x32_bf16(X[7], B1[4*(b)+3][0], a10, 0,0,0); \
    a11 = __builtin_amdgcn_mfma_f32_16x16x32_bf16(X[7], B1[4*(b)+3][1], a11, 0,0,0); \
  } while (0)

// phase-2 tiled h reads: slab base = kb/8 + 16b + 4i (+slabL)
#define P2ISSUE(b, X) do {                                                    \
    const short* h_ = hb + (size_t)(kb / 8 + 16 * (b) + slabL) * 1024;        \
    LLCLD(X[0], (h_ + rowoff0));           LLCLD(X[1], (h_ + rowoff1));       \
    LLCLD(X[2], (h_ + 4096 + rowoff0));    LLCLD(X[3], (h_ + 4096 + rowoff1)); \
    LLCLD(X[4], (h_ + 8192 + rowoff0));    LLCLD(X[5], (h_ + 8192 + rowoff1)); \
    LLCLD(X[6], (h_ + 12288 + rowoff0));   LLCLD(X[7], (h_ + 12288 + rowoff1)); \
  } while (0)

#define P2MFMA(b, X) do {                                                     \
    c00 = __builtin_amdgcn_mfma_f32_16x16x32_bf16(X[0], B2[4*(b)+0][0], c00, 0,0,0); \
    c01 = __builtin_amdgcn_mfma_f32_16x16x32_bf16(X[0], B2[4*(b)+0][1], c01, 0,0,0); \
    c10 = __builtin_amdgcn_mfma_f32_16x16x32_bf16(X[1], B2[4*(b)+0][0], c10, 0,0,0); \
    c11 = __builtin_amdgcn_mfma_f32_16x16x32_bf16(X[1], B2[4*(b)+0][1], c11, 0,0,0); \
    c00 = __builtin_amdgcn_mfma_f32_16x16x32_bf16(X[2], B2[4*(b)+1][0], c00, 0,0,0); \
    c01 = __builtin_amdgcn_mfma_f32_16x16x32_bf16(X[2], B2[4*(b)+1][1], c01, 0,0,0); \
    c10 = __builtin_amdgcn_mfma_f32_16x16x32_bf16(X[3], B2[4*(b)+1][0], c10, 0,0,0); \
    c11 = __builtin_amdgcn_mfma_f32_16x16x32_bf16(X[3], B2[4*(b)+1][1], c11, 0,0,0); \
    c00 = __builtin_amdgcn_mfma_f32_16x16x32_bf16(X[4], B2[4*(b)+2][0], c00, 0,0,0); \
    c01 = __builtin_amdgcn_mfma_f32_16x16x32_bf16(X[4], B2[4*(b)+2][1], c01, 0,0,0); \
    c10 = __builtin_amdgcn_mfma_f32_16x16x32_bf16(X[5], B2[4*(b)+2][0], c10, 0,0,0); \
    c11 = __builtin_amdgcn_mfma_f32_16x16x32_bf16(X[5], B2[4*(b)+2][1], c11, 0,0,0); \
    c00 = __builtin_amdgcn_mfma_f32_16x16x32_bf16(X[6], B2[4*(b)+3][0], c00, 0,0,0); \
    c01 = __builtin_amdgcn_mfma_f32_16x16x32_bf16(X[6], B2[4*(b)+3][1], c01, 0,0,0); \
    c10 = __builtin_amdgcn_mfma_f32_16x16x32_bf16(X[7], B2[4*(b)+3][0], c10, 0,0,0); \
    c11 = __builtin_amdgcn_mfma_f32_16x16x32_bf16(X[7], B2[4*(b)+3][1], c11, 0,0,0); \
  } while (0)

__global__ __launch_bounds__(256, 1)
void resrnn_kernel(const float* __restrict__ inp, const float* __restrict__ W1,
                   const float* __restrict__ b1f, const float* __restrict__ W2,
                   const float* __restrict__ b2f, float* __restrict__ out,
                   unsigned char* __restrict__ ws)
{
  const int tid   = threadIdx.x;
  const int bid   = blockIdx.x;
  const int group = bid & 3;        // 4 independent batch groups (32 rows each)
  const int chunk = bid >> 2;       // 64 N-chunks of 32 cols
  const int mbase = group * 32;
  const int n0    = chunk * 32;
  const int wave  = tid >> 6;
  const int lane  = tid & 63;
  const int l15   = lane & 15;
  const int q8    = (lane >> 4) * 8;
  const int kb    = wave * 512;     // K split 4 ways across waves
  const int slabL = lane >> 4;      // tiled-read slab offset per lane quad

  // per-group flag arrays: 64 chunks x 64B slots (16 u32 stride), monotone gens
  unsigned* sgen = (unsigned*)(ws + group * 8192);          // S-chunk ready: value t+1
  unsigned* hgen = (unsigned*)(ws + group * 8192 + 4096);   // h-chunk ready: value t+1
  // R15 tiled buffers (same sizes/offsets as row-major predecessors):
  // SfT[248 kblk][128 row][8] f32 ; SbT[248][128][8] bf16 ; hbT[256][128][8] bf16
  float* Sf0 = (float*)(ws + 32768);                 // fp32 state master, ping
  float* Sf1 = (float*)(ws + 32768 + 1015808);       // pong
  short* Sb0 = (short*)(ws + 32768 + 2031616);       // bf16 state, ping
  short* Sb1 = (short*)(ws + 32768 + 2539520);       // pong
  short* hb  = (short*)(ws + 32768 + 3047424);       // bf16 h buffer (tiled)

  __shared__ float red[4][16][65];  // +1 pad: conflict-free cross-wave reduce

  // ---- one-time: load & convert weight B-fragments into registers ----
  // B-frag layout (verified m89): n = lane&15 (row of W), k = (lane>>4)*8+j contiguous
  short8 B1[16][2], B2[16][2];
#pragma unroll
  for (int ks = 0; ks < 16; ++ks) {
#pragma unroll
    for (int nt = 0; nt < 2; ++nt) {
      const float* p1 = W1 + (size_t)(n0 + nt * 16 + l15) * WID + (kb + ks * 32 + q8);
      B1[ks][nt] = pack8(*(const f32x4*)p1, *(const f32x4*)(p1 + 4));
      const float* p2 = W2 + (size_t)(n0 + nt * 16 + l15) * WID + (kb + ks * 32 + q8);
      B2[ks][nt] = pack8(*(const f32x4*)p2, *(const f32x4*)(p2 + 4));
    }
  }

  const int m0 = mbase + l15;        // A-frag rows (m-tile 0)
  const int m1 = mbase + 16 + l15;   // m-tile 1
  const int rowoff0 = (mbase + l15) * 8;        // shorts/floats into a slab
  const int rowoff1 = rowoff0 + 128;            // +16 rows

  // R15 epilogue thread-remap (bijection over 32 rows x 8 col-quads):
  // ml = (tid&63)>>1, nl = wave*8 + (tid&1)*4 -> wave's stores are contiguous
  const int ml   = (tid & 63) >> 1;
  const int nl   = ((tid >> 6) << 3) + ((tid & 1) << 2);
  const int mrow = mbase + ml;
  const int c0   = n0 + nl;          // this thread's absolute output column
  // tiled store/load offset: slab n0/8+wave, row mrow, elem (tid&1)*4
  const size_t toff = (size_t)(n0 / 8 + wave) * 1024 + (size_t)mrow * 8
                    + (size_t)((tid & 1) << 2);

  // biases for this thread's 4 output columns, loaded once (constant over t)
  const f32x4 b1r = *(const f32x4*)(b1f + c0);
  const f32x4 b2r = *(const f32x4*)(b2f + c0);

  // phase-1 wait setup: lanes 0..15 poll the 16 A-operand producers;
  // lane 16 polls chunk-2 (covers the hoisted fp32 prev read).
  const int p1pc = 16 * wave + l15 - 2;
  const bool p1needA = (lane < 16) && (p1pc >= 0);
  const bool p1needB = (lane == 16) && (chunk >= 2);
  const unsigned* p1fp =
      p1needA ? (sgen + p1pc * 16)
              : (sgen + (chunk >= 2 ? chunk - 2 : 0) * 16);
  // phase-2 wait setup: lanes 0..15 poll h-chunks 16w+l15
  const unsigned* p2fp = hgen + (16 * wave + l15) * 16;

  short8 xa[8], xb[8];   // double-buffered in-flight operand blocks

#pragma unroll 1
  for (int t = 0; t < NSTEPS; ++t) {
    const float* SfOld = (t & 1) ? Sf1 : Sf0;
    float*       SfNew = (t & 1) ? Sf0 : Sf1;
    const short* SbOld = (t & 1) ? Sb1 : Sb0;
    short*       SbNew = (t & 1) ? Sb0 : Sb1;

    // ================= phase 1: u = s_in @ W1^T ; h = |u + b1| =================
    f32x4 a00{}, a01{}, a10{}, a11{};
    f32x4 prevv;
    if (t == 0) {
      // state is zero: only the x_t part contributes (wave 0, ks 0..1)
      prevv = (c0 < 64) ? *(const f32x4*)(inp + (size_t)mrow * 64 + c0)
                        : f32x4{0.f, 0.f, 0.f, 0.f};
      if (kb == 0) {
        const float* q0_ = inp + (size_t)m0 * 64 + q8;
        const float* q1_ = inp + (size_t)m1 * 64 + q8;
        short8 x0 = pack8(*(const f32x4*)q0_, *(const f32x4*)(q0_ + 4));
        short8 x1 = pack8(*(const f32x4*)q1_, *(const f32x4*)(q1_ + 4));
        short8 x2 = pack8(*(const f32x4*)(q0_ + 32), *(const f32x4*)(q0_ + 36));
        short8 x3 = pack8(*(const f32x4*)(q1_ + 32), *(const f32x4*)(q1_ + 36));
        a00 = __builtin_amdgcn_mfma_f32_16x16x32_bf16(x0, B1[0][0], a00, 0, 0, 0);
        a01 = __builtin_amdgcn_mfma_f32_16x16x32_bf16(x0, B1[0][1], a01, 0, 0, 0);
        a10 = __builtin_amdgcn_mfma_f32_16x16x32_bf16(x1, B1[0][0], a10, 0, 0, 0);
        a11 = __builtin_amdgcn_mfma_f32_16x16x32_bf16(x1, B1[0][1], a11, 0, 0, 0);
        a00 = __builtin_amdgcn_mfma_f32_16x16x32_bf16(x2, B1[1][0], a00, 0, 0, 0);
        a01 = __builtin_amdgcn_mfma_f32_16x16x32_bf16(x2, B1[1][1], a01, 0, 0, 0);
        a10 = __builtin_amdgcn_mfma_f32_16x16x32_bf16(x3, B1[1][0], a10, 0, 0, 0);
        a11 = __builtin_amdgcn_mfma_f32_16x16x32_bf16(x3, B1[1][1], a11, 0, 0, 0);
      }
    } else {
      // ONE sticky wait for all of this wave's producers (before any issue,
      // so the poll's compiler vmcnt(0) can't drain the load pipeline)
      {
        const unsigned tgt = (unsigned)t;
        bool pend = p1needA || p1needB;
        for (;;) {
          if (pend && ald32(p1fp) >= tgt) pend = false;
          if (__ballot(pend) == 0ull) break;
        }
      }
      // hoisted epilogue prev (producer chunk-2 covered by lane-16 wait):
      // tiled SfT read at toff-8192 (slab shift of 8 = the 64-col shift)
      if (c0 < 64) {
        prevv = *(const f32x4*)(inp + ((size_t)t * NB + mrow) * 64 + c0);
      } else {
        LLCLD(prevv, (SfOld + toff - 8192));
      }
      // counted-vmcnt pipeline: block b+1's loads fly under block b's MFMAs
      P1ISSUE(0, xa); P1ISSUE(1, xb);
      VMW(8);  P1MFMA(0, xa);
      P1ISSUE(2, xa);
      VMW(8);  P1MFMA(1, xb);
      P1ISSUE(3, xb);
      VMW(8);  P1MFMA(2, xa);
      VMW(0);  P1MFMA(3, xb);
    }
#pragma unroll
    for (int r = 0; r < 4; ++r) {            // ridx = mt*8 + nt*4 + r
      red[wave][r][lane]      = a00[r];
      red[wave][4 + r][lane]  = a01[r];
      red[wave][8 + r][lane]  = a10[r];
      red[wave][12 + r][lane] = a11[r];
    }
    __syncthreads();
    {
      short4v hv;
#pragma unroll
      for (int j = 0; j < 4; ++j) {
        const int nn   = nl + j;
        const int lidx = ((ml >> 2) & 3) * 16 + (nn & 15);   // C layout: lane=(row>>2)*16+col
        const int ridx = (ml >> 4) * 8 + (nn >> 4) * 4 + (ml & 3);
        float s = red[0][ridx][lidx] + red[1][ridx][lidx]
                + red[2][ridx][lidx] + red[3][ridx][lidx];
        s += b1r[j];
        hv[j] = f2bf(fabsf(s));
      }
      union { short4v s; u64 u; } hu; hu.s = hv;
      ast64(hb + toff, hu.u);   // tiled h store: wave-contiguous 512B
    }
    __syncthreads();   // all 4 waves' h stores drained (vmcnt0) before signal
    if (tid == 0)
      __hip_atomic_store(hgen + chunk * 16, (unsigned)t + 1,
                         __ATOMIC_RELAXED, __HIP_MEMORY_SCOPE_AGENT);

    // ================= phase 2: g = h @ W2^T ; state update =================
    f32x4 c00{}, c01{}, c10{}, c11{};
    {
      {  // one sticky wait for this wave's 16 h-producers
        const unsigned tgt = (unsigned)t + 1;
        bool pend = (lane < 16);
        for (;;) {
          if (pend && ald32(p2fp) >= tgt) pend = false;
          if (__ballot(pend) == 0ull) break;
        }
      }
      P2ISSUE(0, xa); P2ISSUE(1, xb);
      VMW(8);  P2MFMA(0, xa);
      P2ISSUE(2, xa);
      VMW(8);  P2MFMA(1, xb);
      P2ISSUE(3, xb);
      VMW(8);  P2MFMA(2, xa);
      VMW(0);  P2MFMA(3, xb);
    }
#pragma unroll
    for (int r = 0; r < 4; ++r) {
      red[wave][r][lane]      = c00[r];
      red[wave][4 + r][lane]  = c01[r];
      red[wave][8 + r][lane]  = c10[r];
      red[wave][12 + r][lane] = c11[r];
    }
    __syncthreads();
    if (t < NSTEPS - 1) {
      if (n0 < SS) {   // cols >= SS are dropped by the shift (except final step)
        f32x4 gv;
#pragma unroll
        for (int j = 0; j < 4; ++j) {
          const int nn   = nl + j;
          const int lidx = ((ml >> 2) & 3) * 16 + (nn & 15);
          const int ridx = (ml >> 4) * 8 + (nn >> 4) * 4 + (ml & 3);
          gv[j] = red[0][ridx][lidx] + red[1][ridx][lidx]
                + red[2][ridx][lidx] + red[3][ridx][lidx] + b2r[j];
        }
        f32x4 sv; short4v sb;
#pragma unroll
        for (int j = 0; j < 4; ++j) {
          float vv = 0.9f * prevv[j] + 0.1f * gv[j];
          sv[j] = vv; sb[j] = f2bf(vv);
        }
        union { f32x4 f; u64 u[2]; } sfu; sfu.f = sv;
        float* pf = SfNew + toff;          // tiled Sf store (wave-contiguous 1KB)
        ast64(pf, sfu.u[0]);
        ast64(pf + 2, sfu.u[1]);
        union { short4v s; u64 u; } sbu; sbu.s = sb;
        ast64(SbNew + toff, sbu.u);        // tiled Sb store (wave-contiguous 512B)
      }
      __syncthreads();   // all 4 waves' S stores drained before signal
      if (tid == 0 && chunk < 62)
        __hip_atomic_store(sgen + chunk * 16, (unsigned)t + 1,
                           __ATOMIC_RELAXED, __HIP_MEMORY_SCOPE_AGENT);
    } else {
      // final step: out[m, :] = 0.9*s_in[m, 1984+o] + 0.1*(g+b2)[m, 1984+o]
      if (n0 >= SS) {
        f32x4 gv;
#pragma unroll
        for (int j = 0; j < 4; ++j) {
          const int nn   = nl + j;
          const int lidx = ((ml >> 2) & 3) * 16 + (nn & 15);
          const int ridx = (ml >> 4) * 8 + (nn >> 4) * 4 + (ml & 3);
          gv[j] = red[0][ridx][lidx] + red[1][ridx][lidx]
                + red[2][ridx][lidx] + red[3][ridx][lidx] + b2r[j];
        }
        f32x4 ov;
#pragma unroll
        for (int j = 0; j < 4; ++j) ov[j] = 0.9f * prevv[j] + 0.1f * gv[j];
        *(f32x4*)(out + (size_t)mrow * 64 + (c0 - SS)) = ov;
      }
    }
  }
}

extern "C" void kernel_launch(void* const* d_in, const int* in_sizes, int n_in,
                              void* d_out, int out_size, void* d_ws, size_t ws_size,
                              hipStream_t stream)
{
  (void)in_sizes; (void)n_in; (void)out_size; (void)ws_size;
  const float* inp = (const float*)d_in[0];
  const float* W1  = (const float*)d_in[1];
  const float* b1  = (const float*)d_in[2];
  const float* W2  = (const float*)d_in[3];
  const float* b2  = (const float*)d_in[4];
  float* out = (float*)d_out;

  // zero the flag area (ws is re-poisoned to 0xAA before every timed launch)
  hipMemsetAsync(d_ws, 0, 32768, stream);
  resrnn_kernel<<<dim3(256), dim3(256), 0, stream>>>(
      inp, W1, b1, W2, b2, out, (unsigned char*)d_ws);
}